// Round 1
// baseline (645.732 us; speedup 1.0000x reference)
//
#include <hip/hip_runtime.h>
#include <math.h>

#define NN 8
#define CC 256        // channels per tensor (concat input has 2*CC = 512)
#define HH 48
#define WW 48
#define HW 2304       // 48*48
#define OCONV 18      // offset-conv output channels (2*K)
#define KTAP 9        // deform taps
#define G1 8          // channel split for offset conv (512/8 = 64 ch/group)
#define G2 8          // channel split for deform conv (256/8 = 32 ch/group)

// ---------------------------------------------------------------------------
// Kernel 1: 5x5 pad-2 conv of concat([query, support]) with w_off[18][512][5][5]
// -> partial sums over channel groups: offs_part[G1][N][18][HW]
// One thread = one pixel, all 18 output channels. 576 blocks x 256.
// ---------------------------------------------------------------------------
__global__ __launch_bounds__(256) void offset_conv_kernel(
    const float* __restrict__ support, const float* __restrict__ query,
    const float* __restrict__ w_off, float* __restrict__ offs_part) {
  const int bid = blockIdx.x;
  const int pb = bid % 9;          // pixel block (9*256 = 2304)
  const int n  = (bid / 9) % NN;
  const int g  = bid / (9 * NN);   // channel group, 64 channels
  const int p  = pb * 256 + threadIdx.x;
  const int y  = p / WW, x = p % WW;

  // Hoist window addresses + border masks (depend only on y,x)
  int   adr[25];
  float msk[25];
#pragma unroll
  for (int u = 0; u < 5; ++u) {
    const int yy = y + u - 2;
    const int yyc = min(max(yy, 0), HH - 1);
    const bool yv = (unsigned)yy < (unsigned)HH;
#pragma unroll
    for (int v = 0; v < 5; ++v) {
      const int xx = x + v - 2;
      const int xxc = min(max(xx, 0), WW - 1);
      const bool ok = yv && ((unsigned)xx < (unsigned)WW);
      adr[u * 5 + v] = yyc * WW + xxc;
      msk[u * 5 + v] = ok ? 1.f : 0.f;
    }
  }

  float acc[OCONV];
#pragma unroll
  for (int o = 0; o < OCONV; ++o) acc[o] = 0.f;

  const int c0 = g * 64;
  for (int ci = 0; ci < 64; ++ci) {
    const int c = c0 + ci;
    // concat([query, support]): channel c < 256 -> query, else support
    const float* plane = (c < CC) ? (query + (size_t)(n * CC + c) * HW)
                                  : (support + (size_t)(n * CC + (c - CC)) * HW);
    float val[25];
#pragma unroll
    for (int t = 0; t < 25; ++t) val[t] = plane[adr[t]] * msk[t];

#pragma unroll
    for (int o = 0; o < OCONV; ++o) {
      const float* wb = w_off + (size_t)(o * (2 * CC) + c) * 25;  // uniform -> s_load
      float a = acc[o];
#pragma unroll
      for (int t = 0; t < 25; ++t) a = fmaf(val[t], wb[t], a);
      acc[o] = a;
    }
  }

  float* dst = offs_part + ((size_t)(g * NN + n) * OCONV) * HW + p;
#pragma unroll
  for (int o = 0; o < OCONV; ++o) dst[(size_t)o * HW] = acc[o];
}

// ---------------------------------------------------------------------------
// Kernel 2: deformable bilinear gather + einsum partials over channel groups
// dyn_part[G2][N][9][HW]. One thread = one pixel. 576 blocks x 256.
// ---------------------------------------------------------------------------
__global__ __launch_bounds__(256) void deform_kernel(
    const float* __restrict__ support, const float* __restrict__ w_kernel,
    const float* __restrict__ offs_part, float* __restrict__ dyn_part) {
  const int bid = blockIdx.x;
  const int pb = bid % 9;
  const int n  = (bid / 9) % NN;
  const int g  = bid / (9 * NN);   // channel group, 32 channels
  const int p  = pb * 256 + threadIdx.x;
  const int y  = p / WW, x = p % WW;

  int   a00[KTAP], a01[KTAP], a10[KTAP], a11[KTAP];
  float w00[KTAP], w01[KTAP], w10[KTAP], w11[KTAP];

#pragma unroll
  for (int k = 0; k < KTAP; ++k) {
    // sum channel-group partials of the offset conv
    float dy = 0.f, dx = 0.f;
#pragma unroll
    for (int gg = 0; gg < G1; ++gg) {
      const float* base = offs_part + ((size_t)(gg * NN + n) * OCONV) * HW + p;
      dy += base[(size_t)(2 * k) * HW];
      dx += base[(size_t)(2 * k + 1) * HW];
    }
    const float sy = (float)(y + k / 3 - 1) + dy;
    const float sx = (float)(x + k % 3 - 1) + dx;
    const float y0 = floorf(sy), x0 = floorf(sx);
    const float ly = sy - y0,  lx = sx - x0;
    const float y1 = y0 + 1.f, x1 = x0 + 1.f;
    const float vy0 = (y0 >= 0.f && y0 <= (float)(HH - 1)) ? 1.f : 0.f;
    const float vy1 = (y1 >= 0.f && y1 <= (float)(HH - 1)) ? 1.f : 0.f;
    const float vx0 = (x0 >= 0.f && x0 <= (float)(WW - 1)) ? 1.f : 0.f;
    const float vx1 = (x1 >= 0.f && x1 <= (float)(WW - 1)) ? 1.f : 0.f;
    const int yi0 = min(max((int)y0, 0), HH - 1);
    const int yi1 = min(max((int)y1, 0), HH - 1);
    const int xi0 = min(max((int)x0, 0), WW - 1);
    const int xi1 = min(max((int)x1, 0), WW - 1);
    a00[k] = yi0 * WW + xi0; a01[k] = yi0 * WW + xi1;
    a10[k] = yi1 * WW + xi0; a11[k] = yi1 * WW + xi1;
    w00[k] = (1.f - ly) * (1.f - lx) * vy0 * vx0;
    w01[k] = (1.f - ly) * lx * vy0 * vx1;
    w10[k] = ly * (1.f - lx) * vy1 * vx0;
    w11[k] = ly * lx * vy1 * vx1;
  }

  float acc[KTAP];
#pragma unroll
  for (int o = 0; o < KTAP; ++o) acc[o] = 0.f;

  const int c0 = g * (CC / G2);
  for (int ci = 0; ci < CC / G2; ++ci) {
    const int c = c0 + ci;
    const float* plane = support + (size_t)(n * CC + c) * HW;
    float vs[KTAP];
#pragma unroll
    for (int k = 0; k < KTAP; ++k) {
      vs[k] = w00[k] * plane[a00[k]] + w01[k] * plane[a01[k]] +
              w10[k] * plane[a10[k]] + w11[k] * plane[a11[k]];
    }
#pragma unroll
    for (int o = 0; o < KTAP; ++o) {
      const float* wb = w_kernel + (size_t)(o * CC + c) * KTAP;  // uniform -> s_load
      float a = acc[o];
#pragma unroll
      for (int k = 0; k < KTAP; ++k) a = fmaf(vs[k], wb[k], a);
      acc[o] = a;
    }
  }

  float* dst = dyn_part + ((size_t)(g * NN + n) * KTAP) * HW + p;
#pragma unroll
  for (int o = 0; o < KTAP; ++o) dst[(size_t)o * HW] = acc[o];
}

// ---------------------------------------------------------------------------
// Kernel 3: reduce channel-group partials + sigmoid
// ---------------------------------------------------------------------------
__global__ __launch_bounds__(256) void finish_kernel(
    const float* __restrict__ dyn_part, float* __restrict__ out) {
  const int i = blockIdx.x * 256 + threadIdx.x;  // over N*9*HW = 165888
  if (i >= NN * KTAP * HW) return;
  float s = 0.f;
#pragma unroll
  for (int g = 0; g < G2; ++g)
    s += dyn_part[(size_t)g * (NN * KTAP * HW) + i];
  out[i] = 1.f / (1.f + __expf(-s));
}

extern "C" void kernel_launch(void* const* d_in, const int* in_sizes, int n_in,
                              void* d_out, int out_size, void* d_ws, size_t ws_size,
                              hipStream_t stream) {
  const float* support  = (const float*)d_in[0];
  const float* query    = (const float*)d_in[1];
  const float* w_off    = (const float*)d_in[2];
  const float* w_kernel = (const float*)d_in[3];
  float* out = (float*)d_out;

  float* offs_part = (float*)d_ws;                                  // G1*N*18*HW floats (10.6 MB)
  float* dyn_part  = offs_part + (size_t)G1 * NN * OCONV * HW;      // G2*N*9*HW floats (5.3 MB)

  offset_conv_kernel<<<9 * NN * G1, 256, 0, stream>>>(support, query, w_off, offs_part);
  deform_kernel<<<9 * NN * G2, 256, 0, stream>>>(support, w_kernel, offs_part, dyn_part);
  finish_kernel<<<(NN * KTAP * HW + 255) / 256, 256, 0, stream>>>(dyn_part, out);
}

// Round 2
// 436.058 us; speedup vs baseline: 1.4808x; 1.4808x over previous
//
#include <hip/hip_runtime.h>
#include <math.h>

#define NN 8
#define CC 256        // channels per tensor (concat input has 2*CC = 512)
#define HH 48
#define WW 48
#define HW 2304       // 48*48
#define OCONV 18      // offset-conv output channels (2*K)
#define KTAP 9        // deform taps
#define G1 16         // channel-split groups for offset conv (512/16 = 32 ch/group)
#define CHUNK 8       // channels staged in LDS at a time
#define G2 16         // channel-split groups for deform conv (256/16 = 16 ch/group)
#define BR 8          // rows per conv block
#define TLR 12        // staged tile rows (BR + 4 halo)
#define TLC 52        // staged tile cols (48 + 4 halo)
#define NSZ (NN * OCONV * HW)   // one group's offset-partial size = 331776

// ---------------------------------------------------------------------------
// Kernel 1: 5x5 pad-2 conv of concat([query, support]) with w_off[18][512][5][5]
// Channel-group partials: offs_part[G1][N][18][HW].
// Block = 384 threads = 8 rows x 48 cols. Input windows staged zero-padded in
// LDS (8 ch x 12x52), so inner loop is ds_read + FMA only (no masks/clamps).
// ---------------------------------------------------------------------------
__global__ __launch_bounds__(384) void offset_conv_kernel(
    const float* __restrict__ support, const float* __restrict__ query,
    const float* __restrict__ w_off, float* __restrict__ offs_part) {
  const int bid = blockIdx.x;
  const int rb = bid % 6;            // row block (6 x 8 rows = 48)
  const int n  = (bid / 6) % NN;
  const int g  = bid / (6 * NN);     // channel group, 32 channels
  const int tid = threadIdx.x;
  const int r0 = rb * BR;
  const int ly = tid / WW;           // 0..7
  const int lx = tid % WW;           // 0..47
  const int p  = (r0 + ly) * WW + lx;

  __shared__ float tile[CHUNK][TLR * TLC];

  float acc[OCONV];
#pragma unroll
  for (int o = 0; o < OCONV; ++o) acc[o] = 0.f;

  const int c0 = g * (2 * CC / G1);  // 32 channels per group

  for (int chunk = 0; chunk < (2 * CC / G1) / CHUNK; ++chunk) {
    // ---- stage CHUNK channels, zero-padded halo ----
    for (int idx = tid; idx < CHUNK * TLR * TLC; idx += 384) {
      const int ci  = idx / (TLR * TLC);
      const int rem = idx % (TLR * TLC);
      const int rr  = rem / TLC;
      const int cc  = rem % TLC;
      const int gy  = r0 - 2 + rr;
      const int gx  = cc - 2;
      const int c   = c0 + chunk * CHUNK + ci;
      const float* plane = (c < CC) ? (query + (size_t)(n * CC + c) * HW)
                                    : (support + (size_t)(n * CC + (c - CC)) * HW);
      float v = 0.f;
      if ((unsigned)gy < (unsigned)HH && (unsigned)gx < (unsigned)WW)
        v = plane[gy * WW + gx];
      tile[ci][rem] = v;
    }
    __syncthreads();

    // ---- compute ----
    for (int ci = 0; ci < CHUNK; ++ci) {
      const int c = c0 + chunk * CHUNK + ci;
      const float* base = &tile[ci][ly * TLC + lx];
      float val[25];
#pragma unroll
      for (int u = 0; u < 5; ++u)
#pragma unroll
        for (int v = 0; v < 5; ++v) val[u * 5 + v] = base[u * TLC + v];

#pragma unroll
      for (int o = 0; o < OCONV; ++o) {
        const float* wb = w_off + (size_t)(o * (2 * CC) + c) * 25;  // uniform -> s_load
        float a = acc[o];
#pragma unroll
        for (int t = 0; t < 25; ++t) a = fmaf(val[t], wb[t], a);
        acc[o] = a;
      }
    }
    __syncthreads();
  }

  float* dst = offs_part + ((size_t)(g * NN + n) * OCONV) * HW + p;
#pragma unroll
  for (int o = 0; o < OCONV; ++o) dst[(size_t)o * HW] = acc[o];
}

// ---------------------------------------------------------------------------
// Kernel 1b: reduce offset partials: offs[i] = sum_g offs_part[g][i]
// ---------------------------------------------------------------------------
__global__ __launch_bounds__(256) void reduce_offs_kernel(
    const float* __restrict__ offs_part, float* __restrict__ offs) {
  const int i = blockIdx.x * 256 + threadIdx.x;
  if (i >= NSZ) return;
  float s = 0.f;
#pragma unroll
  for (int g = 0; g < G1; ++g) s += offs_part[(size_t)g * NSZ + i];
  offs[i] = s;
}

// ---------------------------------------------------------------------------
// Kernel 2: deformable bilinear gather + einsum partials over channel groups
// dyn_part[G2][N][9][HW]. One thread = one pixel.
// ---------------------------------------------------------------------------
__global__ __launch_bounds__(256) void deform_kernel(
    const float* __restrict__ support, const float* __restrict__ w_kernel,
    const float* __restrict__ offs, float* __restrict__ dyn_part) {
  const int bid = blockIdx.x;
  const int pb = bid % 9;
  const int n  = (bid / 9) % NN;
  const int g  = bid / (9 * NN);   // channel group, 16 channels
  const int p  = pb * 256 + threadIdx.x;
  const int y  = p / WW, x = p % WW;

  int   a00[KTAP], a01[KTAP], a10[KTAP], a11[KTAP];
  float w00[KTAP], w01[KTAP], w10[KTAP], w11[KTAP];

#pragma unroll
  for (int k = 0; k < KTAP; ++k) {
    const float dy = offs[(size_t)(n * OCONV + 2 * k) * HW + p];
    const float dx = offs[(size_t)(n * OCONV + 2 * k + 1) * HW + p];
    const float sy = (float)(y + k / 3 - 1) + dy;
    const float sx = (float)(x + k % 3 - 1) + dx;
    const float y0 = floorf(sy), x0 = floorf(sx);
    const float ly = sy - y0,  lx = sx - x0;
    const float y1 = y0 + 1.f, x1 = x0 + 1.f;
    const float vy0 = (y0 >= 0.f && y0 <= (float)(HH - 1)) ? 1.f : 0.f;
    const float vy1 = (y1 >= 0.f && y1 <= (float)(HH - 1)) ? 1.f : 0.f;
    const float vx0 = (x0 >= 0.f && x0 <= (float)(WW - 1)) ? 1.f : 0.f;
    const float vx1 = (x1 >= 0.f && x1 <= (float)(WW - 1)) ? 1.f : 0.f;
    const int yi0 = min(max((int)y0, 0), HH - 1);
    const int yi1 = min(max((int)y1, 0), HH - 1);
    const int xi0 = min(max((int)x0, 0), WW - 1);
    const int xi1 = min(max((int)x1, 0), WW - 1);
    a00[k] = yi0 * WW + xi0; a01[k] = yi0 * WW + xi1;
    a10[k] = yi1 * WW + xi0; a11[k] = yi1 * WW + xi1;
    w00[k] = (1.f - ly) * (1.f - lx) * vy0 * vx0;
    w01[k] = (1.f - ly) * lx * vy0 * vx1;
    w10[k] = ly * (1.f - lx) * vy1 * vx0;
    w11[k] = ly * lx * vy1 * vx1;
  }

  float acc[KTAP];
#pragma unroll
  for (int o = 0; o < KTAP; ++o) acc[o] = 0.f;

  const int c0 = g * (CC / G2);
  for (int ci = 0; ci < CC / G2; ++ci) {
    const int c = c0 + ci;
    const float* plane = support + (size_t)(n * CC + c) * HW;
    float vs[KTAP];
#pragma unroll
    for (int k = 0; k < KTAP; ++k) {
      vs[k] = w00[k] * plane[a00[k]] + w01[k] * plane[a01[k]] +
              w10[k] * plane[a10[k]] + w11[k] * plane[a11[k]];
    }
#pragma unroll
    for (int o = 0; o < KTAP; ++o) {
      const float* wb = w_kernel + (size_t)(o * CC + c) * KTAP;  // uniform -> s_load
      float a = acc[o];
#pragma unroll
      for (int k = 0; k < KTAP; ++k) a = fmaf(vs[k], wb[k], a);
      acc[o] = a;
    }
  }

  float* dst = dyn_part + ((size_t)(g * NN + n) * KTAP) * HW + p;
#pragma unroll
  for (int o = 0; o < KTAP; ++o) dst[(size_t)o * HW] = acc[o];
}

// ---------------------------------------------------------------------------
// Kernel 3: reduce channel-group partials + sigmoid
// ---------------------------------------------------------------------------
__global__ __launch_bounds__(256) void finish_kernel(
    const float* __restrict__ dyn_part, float* __restrict__ out) {
  const int i = blockIdx.x * 256 + threadIdx.x;  // over N*9*HW = 165888
  if (i >= NN * KTAP * HW) return;
  float s = 0.f;
#pragma unroll
  for (int g = 0; g < G2; ++g)
    s += dyn_part[(size_t)g * (NN * KTAP * HW) + i];
  out[i] = 1.f / (1.f + __expf(-s));
}

extern "C" void kernel_launch(void* const* d_in, const int* in_sizes, int n_in,
                              void* d_out, int out_size, void* d_ws, size_t ws_size,
                              hipStream_t stream) {
  const float* support  = (const float*)d_in[0];
  const float* query    = (const float*)d_in[1];
  const float* w_off    = (const float*)d_in[2];
  const float* w_kernel = (const float*)d_in[3];
  float* out = (float*)d_out;

  // ws layout: [offs 1.33MB][dyn_part 10.6MB overlapping offs_part 21.2MB]
  // offs_part is dead after reduce_offs, so dyn_part may alias it.
  float* offs      = (float*)d_ws;                       // N*18*HW floats
  float* offs_part = offs + (size_t)NSZ;                 // G1*N*18*HW floats
  float* dyn_part  = offs + (size_t)NSZ;                 // G2*N*9*HW floats (aliases offs_part)

  offset_conv_kernel<<<6 * NN * G1, 384, 0, stream>>>(support, query, w_off, offs_part);
  reduce_offs_kernel<<<(NSZ + 255) / 256, 256, 0, stream>>>(offs_part, offs);
  deform_kernel<<<9 * NN * G2, 256, 0, stream>>>(support, w_kernel, offs, dyn_part);
  finish_kernel<<<(NN * KTAP * HW + 255) / 256, 256, 0, stream>>>(dyn_part, out);
}

// Round 3
// 171.806 us; speedup vs baseline: 3.7585x; 2.5381x over previous
//
#include <hip/hip_runtime.h>
#include <math.h>

#define NN 8
#define CC 256        // channels per tensor (concat input has 2*CC = 512)
#define HH 48
#define WW 48
#define HW 2304       // 48*48
#define OCONV 18      // offset-conv output channels (2*K)
#define KTAP 9        // deform taps
#define G1 16         // split-K groups for offset conv (512/16 = 32 ch/group)
#define G2 16         // channel-split groups for deform conv (256/16 = 16 ch/group)
#define NSZ (NN * OCONV * HW)   // 331776
#define DSZ (NN * KTAP * HW)    // 165888

#define TLR 12        // staged tile rows (8 + 4 halo)
#define TLC 52        // staged tile cols (48 + 4 halo)
#define NSITE (TLR * TLC)       // 624 spatial sites
#define SITE_B 80     // bytes per site: 32ch x bf16 = 64B + 16B pad (16B-aligned, 4-way conflict max)

typedef __attribute__((ext_vector_type(8))) short short8;   // 8 bf16 (4 VGPRs)
typedef __attribute__((ext_vector_type(16))) float f32x16;  // 32x32 MFMA acc

static __device__ __forceinline__ unsigned short f2bf(float f) {
  unsigned u = __float_as_uint(f);
  unsigned r = (u + 0x7fffu + ((u >> 16) & 1u)) >> 16;   // round-to-nearest-even
  return (unsigned short)r;
}

// ---------------------------------------------------------------------------
// Kernel 0: transform w_off[18][512][5][5] into MFMA A-fragment layout:
// Wm[t][cb][o][j] (bf16), t=tap(25), cb=channel-block(64), o=row(32, pad>=18), j=0..7
// A-frag for lane l, tap t, k-chunk: one contiguous 16B load.
// ---------------------------------------------------------------------------
__global__ __launch_bounds__(256) void prep_wm_kernel(
    const float* __restrict__ w_off, unsigned short* __restrict__ Wm) {
  const int i = blockIdx.x * 256 + threadIdx.x;
  if (i >= 25 * 64 * 32 * 8) return;
  const int j  = i & 7;
  const int o  = (i >> 3) & 31;
  const int cb = (i >> 8) & 63;
  const int t  = i >> 14;         // 0..24
  float v = 0.f;
  if (o < OCONV) v = w_off[(size_t)(o * (2 * CC) + cb * 8 + j) * 25 + t];
  Wm[i] = f2bf(v);
}

// ---------------------------------------------------------------------------
// Kernel 1: offset conv as 25 shifted GEMMs, bf16 MFMA 32x32x16.
// Block: 384 thr = 6 waves, pixel tile 8 rows x 48. K-group = 32 channels.
// LDS: [site=rr*52+cc][ch] bf16, site stride 80B. B-frag = 1 ds_read_b128.
// offs_part[G1][N][18][HW] partials (f32).
// ---------------------------------------------------------------------------
__global__ __launch_bounds__(384) void offset_conv_mfma(
    const float* __restrict__ support, const float* __restrict__ query,
    const unsigned short* __restrict__ Wm, float* __restrict__ offs_part) {
  const int bid = blockIdx.x;
  const int rb = bid % 6;            // row block (6 x 8 rows)
  const int n  = (bid / 6) % NN;
  const int g  = bid / (6 * NN);     // K-group: channels [g*32, g*32+32)
  const int tid = threadIdx.x;
  const int r0 = rb * 8;

  __shared__ __align__(16) char lds[NSITE * SITE_B];

  // ---- stage 32 channels of rows r0-2..r0+9, cols -2..49 (zero-padded) ----
  // group g<8 -> query channels g*32.. ; g>=8 -> support channels (g-8)*32..
  const float* src = (g < 8) ? (query + ((size_t)n * CC + g * 32) * HW)
                             : (support + ((size_t)n * CC + (g - 8) * 32) * HW);
  for (int cq = 0; cq < 8; ++cq) {           // channel quads
    const float* srcq = src + (size_t)(cq * 4) * HW;
    for (int s = tid; s < NSITE; s += 384) {
      const int rr = s / TLC, cc = s % TLC;
      const int gy = r0 - 2 + rr, gx = cc - 2;
      const bool ok = ((unsigned)gy < (unsigned)HH) && ((unsigned)gx < (unsigned)WW);
      const float* pp = srcq + gy * WW + gx;
      const float f0 = ok ? pp[0] : 0.f;
      const float f1 = ok ? pp[HW] : 0.f;
      const float f2 = ok ? pp[2 * HW] : 0.f;
      const float f3 = ok ? pp[3 * HW] : 0.f;
      const unsigned lo = (unsigned)f2bf(f0) | ((unsigned)f2bf(f1) << 16);
      const unsigned hi = (unsigned)f2bf(f2) | ((unsigned)f2bf(f3) << 16);
      *(uint2*)(lds + s * SITE_B + cq * 8) = make_uint2(lo, hi);
    }
  }
  __syncthreads();

  // ---- MFMA: acc[32 outs][32 pixels], 2 pixel-tiles per wave ----
  const int w      = tid >> 6;     // wave 0..5 -> pixels [64w, 64w+64)
  const int l      = tid & 63;
  const int lane31 = l & 31;
  const int half   = l >> 5;       // k-group half

  f32x16 acc0 = {0.f, 0.f, 0.f, 0.f, 0.f, 0.f, 0.f, 0.f,
                 0.f, 0.f, 0.f, 0.f, 0.f, 0.f, 0.f, 0.f};
  f32x16 acc1 = acc0;

  const int j0 = w * 64 + lane31;      // pixel (nt=0)
  const int j1 = j0 + 32;              // pixel (nt=1)
  const int base0 = ((j0 / 48) * TLC + (j0 % 48)) * SITE_B + half * 16;
  const int base1 = ((j1 / 48) * TLC + (j1 % 48)) * SITE_B + half * 16;

  const short8* __restrict__ wmp = (const short8*)Wm;  // indexed in 16B units
  const int wbase = g * 4 + half;      // + t*64 + kk*2

#pragma unroll
  for (int t = 0; t < 25; ++t) {
    const int u = t / 5, v = t % 5;
    const int off = u * (TLC * SITE_B) + v * SITE_B;   // compile-time per t
    const short8 a0 = wmp[(t * 64 + wbase) * 32 + lane31];       // kk=0
    const short8 a1 = wmp[(t * 64 + wbase + 2) * 32 + lane31];   // kk=1
    const short8 b00 = *(const short8*)(lds + base0 + off);
    const short8 b01 = *(const short8*)(lds + base0 + off + 32);
    const short8 b10 = *(const short8*)(lds + base1 + off);
    const short8 b11 = *(const short8*)(lds + base1 + off + 32);
    acc0 = __builtin_amdgcn_mfma_f32_32x32x16_bf16(a0, b00, acc0, 0, 0, 0);
    acc0 = __builtin_amdgcn_mfma_f32_32x32x16_bf16(a1, b01, acc0, 0, 0, 0);
    acc1 = __builtin_amdgcn_mfma_f32_32x32x16_bf16(a0, b10, acc1, 0, 0, 0);
    acc1 = __builtin_amdgcn_mfma_f32_32x32x16_bf16(a1, b11, acc1, 0, 0, 0);
  }

  // ---- epilogue: C/D layout col=lane&31, row=(r&3)+8*(r>>2)+4*(lane>>5) ----
  float* dst = offs_part + ((size_t)(g * NN + n) * OCONV) * HW + r0 * WW;
#pragma unroll
  for (int r = 0; r < 16; ++r) {
    const int o = (r & 3) + 8 * (r >> 2) + 4 * half;
    if (o < OCONV) {
      dst[(size_t)o * HW + j0] = acc0[r];
      dst[(size_t)o * HW + j1] = acc1[r];
    }
  }
}

// ---------------------------------------------------------------------------
// Kernel 1b: reduce offset partials
// ---------------------------------------------------------------------------
__global__ __launch_bounds__(256) void reduce_offs_kernel(
    const float* __restrict__ offs_part, float* __restrict__ offs) {
  const int i = blockIdx.x * 256 + threadIdx.x;
  if (i >= NSZ) return;
  float s = 0.f;
#pragma unroll
  for (int g = 0; g < G1; ++g) s += offs_part[(size_t)g * NSZ + i];
  offs[i] = s;
}

// ---------------------------------------------------------------------------
// Kernel 2: deformable bilinear gather + einsum partials; support plane
// staged in LDS per channel so gathers are ds_read, not L2.
// ---------------------------------------------------------------------------
__global__ __launch_bounds__(256) void deform_kernel(
    const float* __restrict__ support, const float* __restrict__ w_kernel,
    const float* __restrict__ offs, float* __restrict__ dyn_part) {
  const int bid = blockIdx.x;
  const int pb = bid % 9;
  const int n  = (bid / 9) % NN;
  const int g  = bid / (9 * NN);   // channel group, 16 channels
  const int tid = threadIdx.x;
  const int p  = pb * 256 + tid;
  const int y  = p / WW, x = p % WW;

  __shared__ float plane_s[HW];

  int   a00[KTAP], a01[KTAP], a10[KTAP], a11[KTAP];
  float w00[KTAP], w01[KTAP], w10[KTAP], w11[KTAP];

#pragma unroll
  for (int k = 0; k < KTAP; ++k) {
    const float dy = offs[(size_t)(n * OCONV + 2 * k) * HW + p];
    const float dx = offs[(size_t)(n * OCONV + 2 * k + 1) * HW + p];
    const float sy = (float)(y + k / 3 - 1) + dy;
    const float sx = (float)(x + k % 3 - 1) + dx;
    const float y0 = floorf(sy), x0 = floorf(sx);
    const float ly = sy - y0,  lx = sx - x0;
    const float y1 = y0 + 1.f, x1 = x0 + 1.f;
    const float vy0 = (y0 >= 0.f && y0 <= (float)(HH - 1)) ? 1.f : 0.f;
    const float vy1 = (y1 >= 0.f && y1 <= (float)(HH - 1)) ? 1.f : 0.f;
    const float vx0 = (x0 >= 0.f && x0 <= (float)(WW - 1)) ? 1.f : 0.f;
    const float vx1 = (x1 >= 0.f && x1 <= (float)(WW - 1)) ? 1.f : 0.f;
    const int yi0 = min(max((int)y0, 0), HH - 1);
    const int yi1 = min(max((int)y1, 0), HH - 1);
    const int xi0 = min(max((int)x0, 0), WW - 1);
    const int xi1 = min(max((int)x1, 0), WW - 1);
    a00[k] = yi0 * WW + xi0; a01[k] = yi0 * WW + xi1;
    a10[k] = yi1 * WW + xi0; a11[k] = yi1 * WW + xi1;
    w00[k] = (1.f - ly) * (1.f - lx) * vy0 * vx0;
    w01[k] = (1.f - ly) * lx * vy0 * vx1;
    w10[k] = ly * (1.f - lx) * vy1 * vx0;
    w11[k] = ly * lx * vy1 * vx1;
  }

  float acc[KTAP];
#pragma unroll
  for (int o = 0; o < KTAP; ++o) acc[o] = 0.f;

  const float* base_sup = support + ((size_t)n * CC + g * (CC / G2)) * HW;
  for (int ci = 0; ci < CC / G2; ++ci) {
    __syncthreads();   // protect previous iteration's reads
    const float* plane = base_sup + (size_t)ci * HW;
    for (int i = tid; i < HW; i += 256) plane_s[i] = plane[i];
    __syncthreads();

    const int c = g * (CC / G2) + ci;
    float vs[KTAP];
#pragma unroll
    for (int k = 0; k < KTAP; ++k) {
      vs[k] = w00[k] * plane_s[a00[k]] + w01[k] * plane_s[a01[k]] +
              w10[k] * plane_s[a10[k]] + w11[k] * plane_s[a11[k]];
    }
#pragma unroll
    for (int o = 0; o < KTAP; ++o) {
      const float* wb = w_kernel + (size_t)(o * CC + c) * KTAP;  // uniform -> s_load
      float a = acc[o];
#pragma unroll
      for (int k = 0; k < KTAP; ++k) a = fmaf(vs[k], wb[k], a);
      acc[o] = a;
    }
  }

  float* dst = dyn_part + ((size_t)(g * NN + n) * KTAP) * HW + p;
#pragma unroll
  for (int o = 0; o < KTAP; ++o) dst[(size_t)o * HW] = acc[o];
}

// ---------------------------------------------------------------------------
// Kernel 3: reduce channel-group partials + sigmoid
// ---------------------------------------------------------------------------
__global__ __launch_bounds__(256) void finish_kernel(
    const float* __restrict__ dyn_part, float* __restrict__ out) {
  const int i = blockIdx.x * 256 + threadIdx.x;
  if (i >= DSZ) return;
  float s = 0.f;
#pragma unroll
  for (int g = 0; g < G2; ++g)
    s += dyn_part[(size_t)g * DSZ + i];
  out[i] = 1.f / (1.f + __expf(-s));
}

extern "C" void kernel_launch(void* const* d_in, const int* in_sizes, int n_in,
                              void* d_out, int out_size, void* d_ws, size_t ws_size,
                              hipStream_t stream) {
  const float* support  = (const float*)d_in[0];
  const float* query    = (const float*)d_in[1];
  const float* w_off    = (const float*)d_in[2];
  const float* w_kernel = (const float*)d_in[3];
  float* out = (float*)d_out;

  // ws: [offs 1.33MB][offs_part 21.2MB (dyn_part 10.6MB aliases it)][Wm 0.82MB]
  float* offs      = (float*)d_ws;                       // NSZ
  float* offs_part = offs + (size_t)NSZ;                 // G1*NSZ
  float* dyn_part  = offs + (size_t)NSZ;                 // G2*DSZ, aliases offs_part (dead)
  unsigned short* Wm = (unsigned short*)(offs_part + (size_t)G1 * NSZ);  // 409600 bf16

  prep_wm_kernel<<<(25 * 64 * 32 * 8 + 255) / 256, 256, 0, stream>>>(w_off, Wm);
  offset_conv_mfma<<<6 * NN * G1, 384, 0, stream>>>(support, query, Wm, offs_part);
  reduce_offs_kernel<<<(NSZ + 255) / 256, 256, 0, stream>>>(offs_part, offs);
  deform_kernel<<<9 * NN * G2, 256, 0, stream>>>(support, w_kernel, offs, dyn_part);
  finish_kernel<<<(DSZ + 255) / 256, 256, 0, stream>>>(dyn_part, out);
}

// Round 4
// 139.257 us; speedup vs baseline: 4.6370x; 1.2337x over previous
//
#include <hip/hip_runtime.h>
#include <math.h>

#define NN 8
#define CC 256        // channels per tensor (concat input has 2*CC = 512)
#define HH 48
#define WW 48
#define HW 2304       // 48*48
#define OCONV 18      // offset-conv output channels (2*K)
#define KTAP 9        // deform taps
#define G1 16         // split-K groups for offset conv (512/16 = 32 ch/group)
#define NSZ (NN * OCONV * HW)   // 331776

#define TLR 12        // conv staged tile rows (8 + 4 halo)
#define TLC 52        // conv staged tile cols (48 + 4 halo)
#define NSITE (TLR * TLC)       // 624 spatial sites
#define SITE_B 80     // bytes per site: 32ch x bf16 = 64B + 16B pad

typedef __attribute__((ext_vector_type(8))) short short8;   // 8 bf16 (4 VGPRs)
typedef __attribute__((ext_vector_type(16))) float f32x16;  // 32x32 MFMA acc

static __device__ __forceinline__ unsigned short f2bf(float f) {
  unsigned u = __float_as_uint(f);
  unsigned r = (u + 0x7fffu + ((u >> 16) & 1u)) >> 16;   // round-to-nearest-even
  return (unsigned short)r;
}

// ---------------------------------------------------------------------------
// Kernel 0a: w_off[18][512][5][5] -> MFMA A-fragment layout Wm[t][cb][o][j]
// ---------------------------------------------------------------------------
__global__ __launch_bounds__(256) void prep_wm_kernel(
    const float* __restrict__ w_off, unsigned short* __restrict__ Wm) {
  const int i = blockIdx.x * 256 + threadIdx.x;
  if (i >= 25 * 64 * 32 * 8) return;
  const int j  = i & 7;
  const int o  = (i >> 3) & 31;
  const int cb = (i >> 8) & 63;
  const int t  = i >> 14;
  float v = 0.f;
  if (o < OCONV) v = w_off[(size_t)(o * (2 * CC) + cb * 8 + j) * 25 + t];
  Wm[i] = f2bf(v);
}

// ---------------------------------------------------------------------------
// Kernel 0b: w_kernel[9][256][9] -> wkT[o][k][c] f32 (channel-last)
// ---------------------------------------------------------------------------
__global__ __launch_bounds__(256) void prep_wkt_kernel(
    const float* __restrict__ w_kernel, float* __restrict__ wkT) {
  const int i = blockIdx.x * 256 + threadIdx.x;
  if (i >= KTAP * KTAP * CC) return;
  const int c = i & 255;
  const int k = (i >> 8) % KTAP;
  const int o = i / (KTAP * 256);
  wkT[i] = w_kernel[(size_t)(o * CC + c) * KTAP + k];
}

// ---------------------------------------------------------------------------
// Kernel 1: offset conv as 25 shifted GEMMs, bf16 MFMA 32x32x16 (unchanged).
// ---------------------------------------------------------------------------
__global__ __launch_bounds__(384) void offset_conv_mfma(
    const float* __restrict__ support, const float* __restrict__ query,
    const unsigned short* __restrict__ Wm, float* __restrict__ offs_part) {
  const int bid = blockIdx.x;
  const int rb = bid % 6;
  const int n  = (bid / 6) % NN;
  const int g  = bid / (6 * NN);
  const int tid = threadIdx.x;
  const int r0 = rb * 8;

  __shared__ __align__(16) char lds[NSITE * SITE_B];

  const float* src = (g < 8) ? (query + ((size_t)n * CC + g * 32) * HW)
                             : (support + ((size_t)n * CC + (g - 8) * 32) * HW);
  for (int cq = 0; cq < 8; ++cq) {
    const float* srcq = src + (size_t)(cq * 4) * HW;
    for (int s = tid; s < NSITE; s += 384) {
      const int rr = s / TLC, cc = s % TLC;
      const int gy = r0 - 2 + rr, gx = cc - 2;
      const bool ok = ((unsigned)gy < (unsigned)HH) && ((unsigned)gx < (unsigned)WW);
      const float* pp = srcq + gy * WW + gx;
      const float f0 = ok ? pp[0] : 0.f;
      const float f1 = ok ? pp[HW] : 0.f;
      const float f2 = ok ? pp[2 * HW] : 0.f;
      const float f3 = ok ? pp[3 * HW] : 0.f;
      const unsigned lo = (unsigned)f2bf(f0) | ((unsigned)f2bf(f1) << 16);
      const unsigned hi = (unsigned)f2bf(f2) | ((unsigned)f2bf(f3) << 16);
      *(uint2*)(lds + s * SITE_B + cq * 8) = make_uint2(lo, hi);
    }
  }
  __syncthreads();

  const int w      = tid >> 6;
  const int l      = tid & 63;
  const int lane31 = l & 31;
  const int half   = l >> 5;

  f32x16 acc0 = {0.f, 0.f, 0.f, 0.f, 0.f, 0.f, 0.f, 0.f,
                 0.f, 0.f, 0.f, 0.f, 0.f, 0.f, 0.f, 0.f};
  f32x16 acc1 = acc0;

  const int j0 = w * 64 + lane31;
  const int j1 = j0 + 32;
  const int base0 = ((j0 / 48) * TLC + (j0 % 48)) * SITE_B + half * 16;
  const int base1 = ((j1 / 48) * TLC + (j1 % 48)) * SITE_B + half * 16;

  const short8* __restrict__ wmp = (const short8*)Wm;
  const int wbase = g * 4 + half;

#pragma unroll
  for (int t = 0; t < 25; ++t) {
    const int u = t / 5, v = t % 5;
    const int off = u * (TLC * SITE_B) + v * SITE_B;
    const short8 a0 = wmp[(t * 64 + wbase) * 32 + lane31];
    const short8 a1 = wmp[(t * 64 + wbase + 2) * 32 + lane31];
    const short8 b00 = *(const short8*)(lds + base0 + off);
    const short8 b01 = *(const short8*)(lds + base0 + off + 32);
    const short8 b10 = *(const short8*)(lds + base1 + off);
    const short8 b11 = *(const short8*)(lds + base1 + off + 32);
    acc0 = __builtin_amdgcn_mfma_f32_32x32x16_bf16(a0, b00, acc0, 0, 0, 0);
    acc0 = __builtin_amdgcn_mfma_f32_32x32x16_bf16(a1, b01, acc0, 0, 0, 0);
    acc1 = __builtin_amdgcn_mfma_f32_32x32x16_bf16(a0, b10, acc1, 0, 0, 0);
    acc1 = __builtin_amdgcn_mfma_f32_32x32x16_bf16(a1, b11, acc1, 0, 0, 0);
  }

  float* dst = offs_part + ((size_t)(g * NN + n) * OCONV) * HW + r0 * WW;
#pragma unroll
  for (int r = 0; r < 16; ++r) {
    const int o = (r & 3) + 8 * (r >> 2) + 4 * half;
    if (o < OCONV) {
      dst[(size_t)o * HW + j0] = acc0[r];
      dst[(size_t)o * HW + j1] = acc1[r];
    }
  }
}

// ---------------------------------------------------------------------------
// Kernel 2: fold split-K offset partials + precompute bilinear params.
// par[n][k][p][8]: {w00,w01,w10,w11, a00,a01,a10,a11} (a* as int bits)
// ---------------------------------------------------------------------------
__global__ __launch_bounds__(256) void param_kernel(
    const float* __restrict__ offs_part, float* __restrict__ par) {
  const int i = blockIdx.x * 256 + threadIdx.x;
  if (i >= NN * KTAP * HW) return;
  const int p = i % HW;
  const int k = (i / HW) % KTAP;
  const int n = i / (KTAP * HW);
  const int y = p / WW, x = p % WW;

  float dy = 0.f, dx = 0.f;
#pragma unroll
  for (int g = 0; g < G1; ++g) {
    const float* base = offs_part + ((size_t)(g * NN + n) * OCONV + 2 * k) * HW + p;
    dy += base[0];
    dx += base[HW];
  }
  const float sy = (float)(y + k / 3 - 1) + dy;
  const float sx = (float)(x + k % 3 - 1) + dx;
  const float y0 = floorf(sy), x0 = floorf(sx);
  const float ly = sy - y0,  lx = sx - x0;
  const float y1 = y0 + 1.f, x1 = x0 + 1.f;
  const float vy0 = (y0 >= 0.f && y0 <= (float)(HH - 1)) ? 1.f : 0.f;
  const float vy1 = (y1 >= 0.f && y1 <= (float)(HH - 1)) ? 1.f : 0.f;
  const float vx0 = (x0 >= 0.f && x0 <= (float)(WW - 1)) ? 1.f : 0.f;
  const float vx1 = (x1 >= 0.f && x1 <= (float)(WW - 1)) ? 1.f : 0.f;
  const int yi0 = min(max((int)y0, 0), HH - 1);
  const int yi1 = min(max((int)y1, 0), HH - 1);
  const int xi0 = min(max((int)x0, 0), WW - 1);
  const int xi1 = min(max((int)x1, 0), WW - 1);

  float* d = par + (size_t)i * 8;
  d[0] = (1.f - ly) * (1.f - lx) * vy0 * vx0;
  d[1] = (1.f - ly) * lx * vy0 * vx1;
  d[2] = ly * (1.f - lx) * vy1 * vx0;
  d[3] = ly * lx * vy1 * vx1;
  int* di = (int*)d;
  di[4] = yi0 * WW + xi0;
  di[5] = yi0 * WW + xi1;
  di[6] = yi1 * WW + xi0;
  di[7] = yi1 * WW + xi1;
}

// ---------------------------------------------------------------------------
// Kernel 3: transpose support[n][c][p] -> supT[n][p][c] (32x32 LDS tiles)
// ---------------------------------------------------------------------------
__global__ __launch_bounds__(256) void transpose_kernel(
    const float* __restrict__ support, float* __restrict__ supT) {
  const int bid = blockIdx.x;         // 8 n * 72 ptiles * 8 ctiles
  const int ct = bid & 7;
  const int pt = (bid >> 3) % 72;
  const int n  = bid / (8 * 72);
  const int p0 = pt * 32, c0 = ct * 32;
  const int tid = threadIdx.x;

  __shared__ float tile[32][33];

  const float* src = support + ((size_t)n * CC + c0) * HW + p0;
#pragma unroll
  for (int j = 0; j < 4; ++j) {
    const int idx = tid + j * 256;
    const int cc = idx >> 5, pp = idx & 31;
    tile[pp][cc] = src[(size_t)cc * HW + pp];
  }
  __syncthreads();

  float* dst = supT + ((size_t)n * HW + p0) * CC + c0;
#pragma unroll
  for (int j = 0; j < 4; ++j) {
    const int idx = tid + j * 256;
    const int pp = idx >> 5, cc = idx & 31;
    dst[(size_t)pp * CC + cc] = tile[pp][cc];
  }
}

// ---------------------------------------------------------------------------
// Kernel 4: deform gather + einsum + sigmoid, channel-last.
// Wave = 4 pixels; 64 lanes x 4 channels = 256. No LDS.
// ---------------------------------------------------------------------------
__global__ __launch_bounds__(256) void deform_kernel(
    const float* __restrict__ supT, const float* __restrict__ wkT,
    const float* __restrict__ par, float* __restrict__ out) {
  const int tid  = threadIdx.x;
  const int wv   = __builtin_amdgcn_readfirstlane(tid >> 6);  // wave 0..3 (uniform)
  const int lane = tid & 63;
  const int bid  = blockIdx.x;        // 1152 = 8 n * 144 chunks
  const int n    = bid / 144;
  const int pq   = (bid % 144) * 16 + wv * 4;   // base pixel of this wave

  const float* sup_n = supT + (size_t)n * HW * CC;
  const int cof = lane * 4;           // this lane's 4 channels

  float acc[KTAP][4];
#pragma unroll
  for (int o = 0; o < KTAP; ++o)
#pragma unroll
    for (int i = 0; i < 4; ++i) acc[o][i] = 0.f;

  for (int k = 0; k < KTAP; ++k) {
    const float* pk = par + (((size_t)n * KTAP + k) * HW + pq) * 8;  // wave-uniform
    const int* pki = (const int*)pk;

    float4 val[4];
#pragma unroll
    for (int i = 0; i < 4; ++i) {
      const float w00 = pk[i * 8 + 0], w01 = pk[i * 8 + 1];
      const float w10 = pk[i * 8 + 2], w11 = pk[i * 8 + 3];
      const int a00 = pki[i * 8 + 4], a01 = pki[i * 8 + 5];
      const int a10 = pki[i * 8 + 6], a11 = pki[i * 8 + 7];
      const float4 v00 = *(const float4*)(sup_n + (size_t)a00 * CC + cof);
      const float4 v01 = *(const float4*)(sup_n + (size_t)a01 * CC + cof);
      const float4 v10 = *(const float4*)(sup_n + (size_t)a10 * CC + cof);
      const float4 v11 = *(const float4*)(sup_n + (size_t)a11 * CC + cof);
      float4 v;
      v.x = w00 * v00.x + w01 * v01.x + w10 * v10.x + w11 * v11.x;
      v.y = w00 * v00.y + w01 * v01.y + w10 * v10.y + w11 * v11.y;
      v.z = w00 * v00.z + w01 * v01.z + w10 * v10.z + w11 * v11.z;
      v.w = w00 * v00.w + w01 * v01.w + w10 * v10.w + w11 * v11.w;
      val[i] = v;
    }

#pragma unroll
    for (int o = 0; o < KTAP; ++o) {
      const float4 wk = *(const float4*)(wkT + ((size_t)o * KTAP + k) * CC + cof);
#pragma unroll
      for (int i = 0; i < 4; ++i) {
        float a = acc[o][i];
        a = fmaf(val[i].x, wk.x, a);
        a = fmaf(val[i].y, wk.y, a);
        a = fmaf(val[i].z, wk.z, a);
        a = fmaf(val[i].w, wk.w, a);
        acc[o][i] = a;
      }
    }
  }

  // reduce across 64 lanes (sum over channels) + sigmoid + store
#pragma unroll
  for (int o = 0; o < KTAP; ++o)
#pragma unroll
    for (int i = 0; i < 4; ++i) {
      float s = acc[o][i];
#pragma unroll
      for (int m = 32; m; m >>= 1) s += __shfl_xor(s, m, 64);
      if (lane == 0)
        out[((size_t)n * KTAP + o) * HW + pq + i] = 1.f / (1.f + __expf(-s));
    }
}

extern "C" void kernel_launch(void* const* d_in, const int* in_sizes, int n_in,
                              void* d_out, int out_size, void* d_ws, size_t ws_size,
                              hipStream_t stream) {
  const float* support  = (const float*)d_in[0];
  const float* query    = (const float*)d_in[1];
  const float* w_off    = (const float*)d_in[2];
  const float* w_kernel = (const float*)d_in[3];
  float* out = (float*)d_out;

  // ws layout (floats). Region A holds offs_part (21.2 MB), then is reused
  // for supT (18.9 MB) after param_kernel consumed the partials.
  float* regionA = (float*)d_ws;
  float* offs_part = regionA;                                   // G1*NSZ
  float* supT      = regionA;                                   // NN*HW*CC (aliases, later)
  float* tail      = regionA + (size_t)G1 * NSZ;
  unsigned short* Wm = (unsigned short*)tail;                   // 409600 bf16 = 204800 f
  float* wkT = tail + 204800;                                   // 20736 f
  float* par = wkT + 20736;                                     // NN*KTAP*HW*8 f

  prep_wm_kernel<<<(25 * 64 * 32 * 8 + 255) / 256, 256, 0, stream>>>(w_off, Wm);
  prep_wkt_kernel<<<(KTAP * KTAP * CC + 255) / 256, 256, 0, stream>>>(w_kernel, wkT);
  offset_conv_mfma<<<6 * NN * G1, 384, 0, stream>>>(support, query, Wm, offs_part);
  param_kernel<<<(NN * KTAP * HW + 255) / 256, 256, 0, stream>>>(offs_part, par);
  transpose_kernel<<<8 * 72 * 8, 256, 0, stream>>>(support, supT);  // overwrites offs_part (dead)
  deform_kernel<<<8 * 144, 256, 0, stream>>>(supT, wkT, par, out);
}

// Round 5
// 110.494 us; speedup vs baseline: 5.8440x; 1.2603x over previous
//
#include <hip/hip_runtime.h>
#include <math.h>

#define NN 8
#define CC 256        // channels per tensor (concat input has 2*CC = 512)
#define HH 48
#define WW 48
#define HW 2304       // 48*48
#define OCONV 18      // offset-conv output channels (2*K)
#define KTAP 9        // deform taps
#define G1 16         // split-K groups for offset conv (512/16 = 32 ch/group)
#define NSZ (NN * OCONV * HW)   // 331776

#define TLR 12        // conv staged tile rows (8 + 4 halo)
#define TLC 52        // conv staged tile cols (48 + 4 halo)
#define NSITE (TLR * TLC)       // 624 spatial sites
#define SITE_B 80     // bytes per site: 32ch x bf16 = 64B + 16B pad

typedef __attribute__((ext_vector_type(8))) short short8;   // 8 bf16 (4 VGPRs)
typedef __attribute__((ext_vector_type(16))) float f32x16;  // 32x32 MFMA acc

static __device__ __forceinline__ unsigned short f2bf(float f) {
  unsigned u = __float_as_uint(f);
  unsigned r = (u + 0x7fffu + ((u >> 16) & 1u)) >> 16;   // round-to-nearest-even
  return (unsigned short)r;
}

// ---------------------------------------------------------------------------
// Kernel 0a: w_off[18][512][5][5] -> MFMA A-fragment layout Wm[t][cb][o][j]
// ---------------------------------------------------------------------------
__global__ __launch_bounds__(256) void prep_wm_kernel(
    const float* __restrict__ w_off, unsigned short* __restrict__ Wm) {
  const int i = blockIdx.x * 256 + threadIdx.x;
  if (i >= 25 * 64 * 32 * 8) return;
  const int j  = i & 7;
  const int o  = (i >> 3) & 31;
  const int cb = (i >> 8) & 63;
  const int t  = i >> 14;
  float v = 0.f;
  if (o < OCONV) v = w_off[(size_t)(o * (2 * CC) + cb * 8 + j) * 25 + t];
  Wm[i] = f2bf(v);
}

// ---------------------------------------------------------------------------
// Kernel 0b: w_kernel[9][256][9] -> wkT[o][k][c] f32 (channel-last)
// ---------------------------------------------------------------------------
__global__ __launch_bounds__(256) void prep_wkt_kernel(
    const float* __restrict__ w_kernel, float* __restrict__ wkT) {
  const int i = blockIdx.x * 256 + threadIdx.x;
  if (i >= KTAP * KTAP * CC) return;
  const int c = i & 255;
  const int k = (i >> 8) % KTAP;
  const int o = i / (KTAP * 256);
  wkT[i] = w_kernel[(size_t)(o * CC + c) * KTAP + k];
}

// ---------------------------------------------------------------------------
// Kernel 1: offset conv as 25 shifted GEMMs, bf16 MFMA 32x32x16.
// XCD-pinned: n = bid % 8 so image n's inputs/outputs stay in one XCD L2.
// ---------------------------------------------------------------------------
__global__ __launch_bounds__(384) void offset_conv_mfma(
    const float* __restrict__ support, const float* __restrict__ query,
    const unsigned short* __restrict__ Wm, float* __restrict__ offs_part) {
  const int bid = blockIdx.x;
  const int n    = bid & 7;          // XCD pin
  const int rest = bid >> 3;         // 0..95
  const int g  = rest / 6;           // K-group
  const int rb = rest % 6;           // row block
  const int tid = threadIdx.x;
  const int r0 = rb * 8;

  __shared__ __align__(16) char lds[NSITE * SITE_B];

  const float* src = (g < 8) ? (query + ((size_t)n * CC + g * 32) * HW)
                             : (support + ((size_t)n * CC + (g - 8) * 32) * HW);
  for (int cq = 0; cq < 8; ++cq) {
    const float* srcq = src + (size_t)(cq * 4) * HW;
    for (int s = tid; s < NSITE; s += 384) {
      const int rr = s / TLC, cc = s % TLC;
      const int gy = r0 - 2 + rr, gx = cc - 2;
      const bool ok = ((unsigned)gy < (unsigned)HH) && ((unsigned)gx < (unsigned)WW);
      const float* pp = srcq + gy * WW + gx;
      const float f0 = ok ? pp[0] : 0.f;
      const float f1 = ok ? pp[HW] : 0.f;
      const float f2 = ok ? pp[2 * HW] : 0.f;
      const float f3 = ok ? pp[3 * HW] : 0.f;
      const unsigned lo = (unsigned)f2bf(f0) | ((unsigned)f2bf(f1) << 16);
      const unsigned hi = (unsigned)f2bf(f2) | ((unsigned)f2bf(f3) << 16);
      *(uint2*)(lds + s * SITE_B + cq * 8) = make_uint2(lo, hi);
    }
  }
  __syncthreads();

  const int w      = tid >> 6;
  const int l      = tid & 63;
  const int lane31 = l & 31;
  const int half   = l >> 5;

  f32x16 acc0 = {0.f, 0.f, 0.f, 0.f, 0.f, 0.f, 0.f, 0.f,
                 0.f, 0.f, 0.f, 0.f, 0.f, 0.f, 0.f, 0.f};
  f32x16 acc1 = acc0;

  const int j0 = w * 64 + lane31;
  const int j1 = j0 + 32;
  const int base0 = ((j0 / 48) * TLC + (j0 % 48)) * SITE_B + half * 16;
  const int base1 = ((j1 / 48) * TLC + (j1 % 48)) * SITE_B + half * 16;

  const short8* __restrict__ wmp = (const short8*)Wm;
  const int wbase = g * 4 + half;

#pragma unroll
  for (int t = 0; t < 25; ++t) {
    const int u = t / 5, v = t % 5;
    const int off = u * (TLC * SITE_B) + v * SITE_B;
    const short8 a0 = wmp[(t * 64 + wbase) * 32 + lane31];
    const short8 a1 = wmp[(t * 64 + wbase + 2) * 32 + lane31];
    const short8 b00 = *(const short8*)(lds + base0 + off);
    const short8 b01 = *(const short8*)(lds + base0 + off + 32);
    const short8 b10 = *(const short8*)(lds + base1 + off);
    const short8 b11 = *(const short8*)(lds + base1 + off + 32);
    acc0 = __builtin_amdgcn_mfma_f32_32x32x16_bf16(a0, b00, acc0, 0, 0, 0);
    acc0 = __builtin_amdgcn_mfma_f32_32x32x16_bf16(a1, b01, acc0, 0, 0, 0);
    acc1 = __builtin_amdgcn_mfma_f32_32x32x16_bf16(a0, b10, acc1, 0, 0, 0);
    acc1 = __builtin_amdgcn_mfma_f32_32x32x16_bf16(a1, b11, acc1, 0, 0, 0);
  }

  float* dst = offs_part + ((size_t)(g * NN + n) * OCONV) * HW + r0 * WW;
#pragma unroll
  for (int r = 0; r < 16; ++r) {
    const int o = (r & 3) + 8 * (r >> 2) + 4 * half;
    if (o < OCONV) {
      dst[(size_t)o * HW + j0] = acc0[r];
      dst[(size_t)o * HW + j1] = acc1[r];
    }
  }
}

// ---------------------------------------------------------------------------
// Kernel 2: fold split-K offset partials + precompute bilinear params.
// par[n][k][p][8]: {w00,w01,w10,w11, a00,a01,a10,a11}. XCD-pinned by n.
// Grid: 648 blocks = 81 per image * 8 images, n = bid % 8.
// ---------------------------------------------------------------------------
__global__ __launch_bounds__(256) void param_kernel(
    const float* __restrict__ offs_part, float* __restrict__ par) {
  const int n  = blockIdx.x & 7;       // XCD pin
  const int j  = blockIdx.x >> 3;      // 0..80
  const int il = j * 256 + threadIdx.x; // 0..20735 within image
  const int p = il % HW;
  const int k = il / HW;
  const int y = p / WW, x = p % WW;

  float dy = 0.f, dx = 0.f;
#pragma unroll
  for (int g = 0; g < G1; ++g) {
    const float* base = offs_part + ((size_t)(g * NN + n) * OCONV + 2 * k) * HW + p;
    dy += base[0];
    dx += base[HW];
  }
  const float sy = (float)(y + k / 3 - 1) + dy;
  const float sx = (float)(x + k % 3 - 1) + dx;
  const float y0 = floorf(sy), x0 = floorf(sx);
  const float ly = sy - y0,  lx = sx - x0;
  const float y1 = y0 + 1.f, x1 = x0 + 1.f;
  const float vy0 = (y0 >= 0.f && y0 <= (float)(HH - 1)) ? 1.f : 0.f;
  const float vy1 = (y1 >= 0.f && y1 <= (float)(HH - 1)) ? 1.f : 0.f;
  const float vx0 = (x0 >= 0.f && x0 <= (float)(WW - 1)) ? 1.f : 0.f;
  const float vx1 = (x1 >= 0.f && x1 <= (float)(WW - 1)) ? 1.f : 0.f;
  const int yi0 = min(max((int)y0, 0), HH - 1);
  const int yi1 = min(max((int)y1, 0), HH - 1);
  const int xi0 = min(max((int)x0, 0), WW - 1);
  const int xi1 = min(max((int)x1, 0), WW - 1);

  float* d = par + ((size_t)n * KTAP * HW + il) * 8;
  d[0] = (1.f - ly) * (1.f - lx) * vy0 * vx0;
  d[1] = (1.f - ly) * lx * vy0 * vx1;
  d[2] = ly * (1.f - lx) * vy1 * vx0;
  d[3] = ly * lx * vy1 * vx1;
  int* di = (int*)d;
  di[4] = yi0 * WW + xi0;
  di[5] = yi0 * WW + xi1;
  di[6] = yi1 * WW + xi0;
  di[7] = yi1 * WW + xi1;
}

// ---------------------------------------------------------------------------
// Kernel 3: transpose support[n][c][p] -> supT[n][p][c]. XCD-pinned by n so
// the dirty lines land in the L2 that deform will read from.
// ---------------------------------------------------------------------------
__global__ __launch_bounds__(256) void transpose_kernel(
    const float* __restrict__ support, float* __restrict__ supT) {
  const int bid = blockIdx.x;         // 4608 = 8 n * (72 ptiles * 8 ctiles)
  const int n    = bid & 7;           // XCD pin
  const int rest = bid >> 3;          // 0..575
  const int pt = rest % 72;
  const int ct = rest / 72;
  const int p0 = pt * 32, c0 = ct * 32;
  const int tid = threadIdx.x;

  __shared__ float tile[32][33];

  const float* src = support + ((size_t)n * CC + c0) * HW + p0;
#pragma unroll
  for (int j = 0; j < 4; ++j) {
    const int idx = tid + j * 256;
    const int cc = idx >> 5, pp = idx & 31;
    tile[pp][cc] = src[(size_t)cc * HW + pp];
  }
  __syncthreads();

  float* dst = supT + ((size_t)n * HW + p0) * CC + c0;
#pragma unroll
  for (int j = 0; j < 4; ++j) {
    const int idx = tid + j * 256;
    const int pp = idx >> 5, cc = idx & 31;
    dst[(size_t)pp * CC + cc] = tile[pp][cc];
  }
}

// ---------------------------------------------------------------------------
// Kernel 4: deform gather + einsum + sigmoid, channel-last, XCD-pinned by n.
// Wave = 4 pixels; 64 lanes x 4 channels = 256. No LDS.
// ---------------------------------------------------------------------------
__global__ __launch_bounds__(256) void deform_kernel(
    const float* __restrict__ supT, const float* __restrict__ wkT,
    const float* __restrict__ par, float* __restrict__ out) {
  const int tid  = threadIdx.x;
  const int wv   = __builtin_amdgcn_readfirstlane(tid >> 6);  // wave 0..3 (uniform)
  const int lane = tid & 63;
  const int bid  = blockIdx.x;        // 1152 = 144 chunks * 8 n
  const int n    = bid & 7;           // XCD pin
  const int pq   = (bid >> 3) * 16 + wv * 4;   // base pixel of this wave

  const float* sup_n = supT + (size_t)n * HW * CC;
  const int cof = lane * 4;           // this lane's 4 channels

  float acc[KTAP][4];
#pragma unroll
  for (int o = 0; o < KTAP; ++o)
#pragma unroll
    for (int i = 0; i < 4; ++i) acc[o][i] = 0.f;

  for (int k = 0; k < KTAP; ++k) {
    const float* pk = par + (((size_t)n * KTAP + k) * HW + pq) * 8;  // wave-uniform
    const int* pki = (const int*)pk;

    float4 val[4];
#pragma unroll
    for (int i = 0; i < 4; ++i) {
      const float w00 = pk[i * 8 + 0], w01 = pk[i * 8 + 1];
      const float w10 = pk[i * 8 + 2], w11 = pk[i * 8 + 3];
      const int a00 = pki[i * 8 + 4], a01 = pki[i * 8 + 5];
      const int a10 = pki[i * 8 + 6], a11 = pki[i * 8 + 7];
      const float4 v00 = *(const float4*)(sup_n + (size_t)a00 * CC + cof);
      const float4 v01 = *(const float4*)(sup_n + (size_t)a01 * CC + cof);
      const float4 v10 = *(const float4*)(sup_n + (size_t)a10 * CC + cof);
      const float4 v11 = *(const float4*)(sup_n + (size_t)a11 * CC + cof);
      float4 v;
      v.x = w00 * v00.x + w01 * v01.x + w10 * v10.x + w11 * v11.x;
      v.y = w00 * v00.y + w01 * v01.y + w10 * v10.y + w11 * v11.y;
      v.z = w00 * v00.z + w01 * v01.z + w10 * v10.z + w11 * v11.z;
      v.w = w00 * v00.w + w01 * v01.w + w10 * v10.w + w11 * v11.w;
      val[i] = v;
    }

#pragma unroll
    for (int o = 0; o < KTAP; ++o) {
      const float4 wk = *(const float4*)(wkT + ((size_t)o * KTAP + k) * CC + cof);
#pragma unroll
      for (int i = 0; i < 4; ++i) {
        float a = acc[o][i];
        a = fmaf(val[i].x, wk.x, a);
        a = fmaf(val[i].y, wk.y, a);
        a = fmaf(val[i].z, wk.z, a);
        a = fmaf(val[i].w, wk.w, a);
        acc[o][i] = a;
      }
    }
  }

  // reduce across 64 lanes (sum over channels) + sigmoid + store
#pragma unroll
  for (int o = 0; o < KTAP; ++o)
#pragma unroll
    for (int i = 0; i < 4; ++i) {
      float s = acc[o][i];
#pragma unroll
      for (int m = 32; m; m >>= 1) s += __shfl_xor(s, m, 64);
      if (lane == 0)
        out[((size_t)n * KTAP + o) * HW + pq + i] = 1.f / (1.f + __expf(-s));
    }
}

extern "C" void kernel_launch(void* const* d_in, const int* in_sizes, int n_in,
                              void* d_out, int out_size, void* d_ws, size_t ws_size,
                              hipStream_t stream) {
  const float* support  = (const float*)d_in[0];
  const float* query    = (const float*)d_in[1];
  const float* w_off    = (const float*)d_in[2];
  const float* w_kernel = (const float*)d_in[3];
  float* out = (float*)d_out;

  // ws layout (floats). Region A holds offs_part (21.2 MB), then is reused
  // for supT (18.9 MB) after param_kernel consumed the partials.
  float* regionA = (float*)d_ws;
  float* offs_part = regionA;                                   // G1*NSZ
  float* supT      = regionA;                                   // NN*HW*CC (aliases, later)
  float* tail      = regionA + (size_t)G1 * NSZ;
  unsigned short* Wm = (unsigned short*)tail;                   // 409600 bf16 = 204800 f
  float* wkT = tail + 204800;                                   // 20736 f
  float* par = wkT + 20736;                                     // NN*KTAP*HW*8 f

  prep_wm_kernel<<<(25 * 64 * 32 * 8 + 255) / 256, 256, 0, stream>>>(w_off, Wm);
  prep_wkt_kernel<<<(KTAP * KTAP * CC + 255) / 256, 256, 0, stream>>>(w_kernel, wkT);
  offset_conv_mfma<<<6 * NN * G1, 384, 0, stream>>>(support, query, Wm, offs_part);
  param_kernel<<<81 * NN, 256, 0, stream>>>(offs_part, par);
  transpose_kernel<<<8 * 72 * 8, 256, 0, stream>>>(support, supT);  // overwrites offs_part (dead)
  deform_kernel<<<144 * 8, 256, 0, stream>>>(supT, wkT, par, out);
}

// Round 6
// 104.822 us; speedup vs baseline: 6.1603x; 1.0541x over previous
//
#include <hip/hip_runtime.h>
#include <math.h>

#define NN 8
#define CC 256        // channels per tensor (concat input has 2*CC = 512)
#define HH 48
#define WW 48
#define HW 2304       // 48*48
#define OCONV 18      // offset-conv output channels (2*K)
#define KTAP 9        // deform taps
#define G1 16         // split-K groups for offset conv (512/16 = 32 ch/group)
#define NSZ (NN * OCONV * HW)   // 331776

#define TLR 12        // conv staged tile rows (8 + 4 halo)
#define TLC 52        // conv staged tile cols (48 + 4 halo)
#define NSITE (TLR * TLC)       // 624 spatial sites
#define SITE_B 80     // bytes per site: 32ch x bf16 = 64B + 16B pad

typedef __attribute__((ext_vector_type(8))) short short8;   // 8 bf16 (4 VGPRs)
typedef __attribute__((ext_vector_type(16))) float f32x16;  // 32x32 MFMA acc

static __device__ __forceinline__ unsigned short f2bf(float f) {
  unsigned u = __float_as_uint(f);
  unsigned r = (u + 0x7fffu + ((u >> 16) & 1u)) >> 16;   // round-to-nearest-even
  return (unsigned short)r;
}
static __device__ __forceinline__ float bflo(unsigned u) {
  return __uint_as_float(u << 16);
}
static __device__ __forceinline__ float bfhi(unsigned u) {
  return __uint_as_float(u & 0xffff0000u);
}

// ---------------------------------------------------------------------------
// Kernel 0a: w_off[18][512][5][5] -> MFMA A-fragment layout Wm[t][cb][o][j]
// ---------------------------------------------------------------------------
__global__ __launch_bounds__(256) void prep_wm_kernel(
    const float* __restrict__ w_off, unsigned short* __restrict__ Wm) {
  const int i = blockIdx.x * 256 + threadIdx.x;
  if (i >= 25 * 64 * 32 * 8) return;
  const int j  = i & 7;
  const int o  = (i >> 3) & 31;
  const int cb = (i >> 8) & 63;
  const int t  = i >> 14;
  float v = 0.f;
  if (o < OCONV) v = w_off[(size_t)(o * (2 * CC) + cb * 8 + j) * 25 + t];
  Wm[i] = f2bf(v);
}

// ---------------------------------------------------------------------------
// Kernel 0b: w_kernel[9][256][9] -> wkT[o][k][c] bf16 (channel-last)
// ---------------------------------------------------------------------------
__global__ __launch_bounds__(256) void prep_wkt_kernel(
    const float* __restrict__ w_kernel, unsigned short* __restrict__ wkT) {
  const int i = blockIdx.x * 256 + threadIdx.x;
  if (i >= KTAP * KTAP * CC) return;
  const int c = i & 255;
  const int k = (i >> 8) % KTAP;
  const int o = i / (KTAP * 256);
  wkT[i] = f2bf(w_kernel[(size_t)(o * CC + c) * KTAP + k]);
}

// ---------------------------------------------------------------------------
// Kernel 1: offset conv as 25 shifted GEMMs, bf16 MFMA 32x32x16.
// XCD-pinned: n = bid % 8.
// ---------------------------------------------------------------------------
__global__ __launch_bounds__(384) void offset_conv_mfma(
    const float* __restrict__ support, const float* __restrict__ query,
    const unsigned short* __restrict__ Wm, float* __restrict__ offs_part) {
  const int bid = blockIdx.x;
  const int n    = bid & 7;          // XCD pin
  const int rest = bid >> 3;         // 0..95
  const int g  = rest / 6;           // K-group
  const int rb = rest % 6;           // row block
  const int tid = threadIdx.x;
  const int r0 = rb * 8;

  __shared__ __align__(16) char lds[NSITE * SITE_B];

  const float* src = (g < 8) ? (query + ((size_t)n * CC + g * 32) * HW)
                             : (support + ((size_t)n * CC + (g - 8) * 32) * HW);
  for (int cq = 0; cq < 8; ++cq) {
    const float* srcq = src + (size_t)(cq * 4) * HW;
    for (int s = tid; s < NSITE; s += 384) {
      const int rr = s / TLC, cc = s % TLC;
      const int gy = r0 - 2 + rr, gx = cc - 2;
      const bool ok = ((unsigned)gy < (unsigned)HH) && ((unsigned)gx < (unsigned)WW);
      const float* pp = srcq + gy * WW + gx;
      const float f0 = ok ? pp[0] : 0.f;
      const float f1 = ok ? pp[HW] : 0.f;
      const float f2 = ok ? pp[2 * HW] : 0.f;
      const float f3 = ok ? pp[3 * HW] : 0.f;
      const unsigned lo = (unsigned)f2bf(f0) | ((unsigned)f2bf(f1) << 16);
      const unsigned hi = (unsigned)f2bf(f2) | ((unsigned)f2bf(f3) << 16);
      *(uint2*)(lds + s * SITE_B + cq * 8) = make_uint2(lo, hi);
    }
  }
  __syncthreads();

  const int w      = tid >> 6;
  const int l      = tid & 63;
  const int lane31 = l & 31;
  const int half   = l >> 5;

  f32x16 acc0 = {0.f, 0.f, 0.f, 0.f, 0.f, 0.f, 0.f, 0.f,
                 0.f, 0.f, 0.f, 0.f, 0.f, 0.f, 0.f, 0.f};
  f32x16 acc1 = acc0;

  const int j0 = w * 64 + lane31;
  const int j1 = j0 + 32;
  const int base0 = ((j0 / 48) * TLC + (j0 % 48)) * SITE_B + half * 16;
  const int base1 = ((j1 / 48) * TLC + (j1 % 48)) * SITE_B + half * 16;

  const short8* __restrict__ wmp = (const short8*)Wm;
  const int wbase = g * 4 + half;

#pragma unroll
  for (int t = 0; t < 25; ++t) {
    const int u = t / 5, v = t % 5;
    const int off = u * (TLC * SITE_B) + v * SITE_B;
    const short8 a0 = wmp[(t * 64 + wbase) * 32 + lane31];
    const short8 a1 = wmp[(t * 64 + wbase + 2) * 32 + lane31];
    const short8 b00 = *(const short8*)(lds + base0 + off);
    const short8 b01 = *(const short8*)(lds + base0 + off + 32);
    const short8 b10 = *(const short8*)(lds + base1 + off);
    const short8 b11 = *(const short8*)(lds + base1 + off + 32);
    acc0 = __builtin_amdgcn_mfma_f32_32x32x16_bf16(a0, b00, acc0, 0, 0, 0);
    acc0 = __builtin_amdgcn_mfma_f32_32x32x16_bf16(a1, b01, acc0, 0, 0, 0);
    acc1 = __builtin_amdgcn_mfma_f32_32x32x16_bf16(a0, b10, acc1, 0, 0, 0);
    acc1 = __builtin_amdgcn_mfma_f32_32x32x16_bf16(a1, b11, acc1, 0, 0, 0);
  }

  float* dst = offs_part + ((size_t)(g * NN + n) * OCONV) * HW + r0 * WW;
#pragma unroll
  for (int r = 0; r < 16; ++r) {
    const int o = (r & 3) + 8 * (r >> 2) + 4 * half;
    if (o < OCONV) {
      dst[(size_t)o * HW + j0] = acc0[r];
      dst[(size_t)o * HW + j1] = acc1[r];
    }
  }
}

// ---------------------------------------------------------------------------
// Kernel 2: fold split-K offset partials + precompute bilinear params.
// par[n][k][p][8]: {w00,w01,w10,w11, a00,a01,a10,a11}. XCD-pinned by n.
// ---------------------------------------------------------------------------
__global__ __launch_bounds__(256) void param_kernel(
    const float* __restrict__ offs_part, float* __restrict__ par) {
  const int n  = blockIdx.x & 7;       // XCD pin
  const int j  = blockIdx.x >> 3;      // 0..80
  const int il = j * 256 + threadIdx.x; // 0..20735 within image
  const int p = il % HW;
  const int k = il / HW;
  const int y = p / WW, x = p % WW;

  float dy = 0.f, dx = 0.f;
#pragma unroll
  for (int g = 0; g < G1; ++g) {
    const float* base = offs_part + ((size_t)(g * NN + n) * OCONV + 2 * k) * HW + p;
    dy += base[0];
    dx += base[HW];
  }
  const float sy = (float)(y + k / 3 - 1) + dy;
  const float sx = (float)(x + k % 3 - 1) + dx;
  const float y0 = floorf(sy), x0 = floorf(sx);
  const float ly = sy - y0,  lx = sx - x0;
  const float y1 = y0 + 1.f, x1 = x0 + 1.f;
  const float vy0 = (y0 >= 0.f && y0 <= (float)(HH - 1)) ? 1.f : 0.f;
  const float vy1 = (y1 >= 0.f && y1 <= (float)(HH - 1)) ? 1.f : 0.f;
  const float vx0 = (x0 >= 0.f && x0 <= (float)(WW - 1)) ? 1.f : 0.f;
  const float vx1 = (x1 >= 0.f && x1 <= (float)(WW - 1)) ? 1.f : 0.f;
  const int yi0 = min(max((int)y0, 0), HH - 1);
  const int yi1 = min(max((int)y1, 0), HH - 1);
  const int xi0 = min(max((int)x0, 0), WW - 1);
  const int xi1 = min(max((int)x1, 0), WW - 1);

  float* d = par + ((size_t)n * KTAP * HW + il) * 8;
  d[0] = (1.f - ly) * (1.f - lx) * vy0 * vx0;
  d[1] = (1.f - ly) * lx * vy0 * vx1;
  d[2] = ly * (1.f - lx) * vy1 * vx0;
  d[3] = ly * lx * vy1 * vx1;
  int* di = (int*)d;
  di[4] = yi0 * WW + xi0;
  di[5] = yi0 * WW + xi1;
  di[6] = yi1 * WW + xi0;
  di[7] = yi1 * WW + xi1;
}

// ---------------------------------------------------------------------------
// Kernel 3: transpose support[n][c][p] -> supT[n][p][c] in bf16 (packed x2).
// XCD-pinned by n.
// ---------------------------------------------------------------------------
__global__ __launch_bounds__(256) void transpose_kernel(
    const float* __restrict__ support, unsigned short* __restrict__ supT) {
  const int bid = blockIdx.x;         // 4608 = 8 n * (72 ptiles * 8 ctiles)
  const int n    = bid & 7;           // XCD pin
  const int rest = bid >> 3;          // 0..575
  const int pt = rest % 72;
  const int ct = rest / 72;
  const int p0 = pt * 32, c0 = ct * 32;
  const int tid = threadIdx.x;

  __shared__ float tile[32][33];

  const float* src = support + ((size_t)n * CC + c0) * HW + p0;
#pragma unroll
  for (int j = 0; j < 4; ++j) {
    const int idx = tid + j * 256;
    const int cc = idx >> 5, pp = idx & 31;
    tile[pp][cc] = src[(size_t)cc * HW + pp];
  }
  __syncthreads();

  // write packed bf16 pairs: 32 p-rows x 16 channel-pairs
#pragma unroll
  for (int j = 0; j < 2; ++j) {
    const int idx = tid + j * 256;
    const int pp = idx >> 4, cp = idx & 15;
    const unsigned lo = f2bf(tile[pp][2 * cp]);
    const unsigned hi = f2bf(tile[pp][2 * cp + 1]);
    unsigned* dst = (unsigned*)(supT + ((size_t)(n * HW + p0 + pp)) * CC + c0);
    dst[cp] = lo | (hi << 16);
  }
}

// ---------------------------------------------------------------------------
// Kernel 4: deform gather + einsum + sigmoid. bf16 supT/wkT, channel-last,
// XCD-pinned. Wave = 2 pixels; 64 lanes x 4 channels. 2304 blocks -> high TLP.
// ---------------------------------------------------------------------------
__global__ __launch_bounds__(256) void deform_kernel(
    const unsigned short* __restrict__ supT, const unsigned short* __restrict__ wkT,
    const float* __restrict__ par, float* __restrict__ out) {
  const int tid  = threadIdx.x;
  const int wv   = __builtin_amdgcn_readfirstlane(tid >> 6);  // wave 0..3
  const int lane = tid & 63;
  const int bid  = blockIdx.x;        // 2304 = 288 chunks * 8 n
  const int n    = bid & 7;           // XCD pin
  const int pq   = (bid >> 3) * 8 + wv * 2;   // base pixel of this wave (2 pixels)

  const unsigned short* sup_n = supT + (size_t)n * HW * CC;
  const int cof = lane * 4;           // this lane's 4 channels

  float acc[KTAP][2];
#pragma unroll
  for (int o = 0; o < KTAP; ++o) { acc[o][0] = 0.f; acc[o][1] = 0.f; }

  for (int k = 0; k < KTAP; ++k) {
    const float* pk = par + (((size_t)n * KTAP + k) * HW + pq) * 8;  // wave-uniform
    const int* pki = (const int*)pk;

    float val[2][4];
#pragma unroll
    for (int i = 0; i < 2; ++i) {
      const float w00 = pk[i * 8 + 0], w01 = pk[i * 8 + 1];
      const float w10 = pk[i * 8 + 2], w11 = pk[i * 8 + 3];
      const int a00 = pki[i * 8 + 4], a01 = pki[i * 8 + 5];
      const int a10 = pki[i * 8 + 6], a11 = pki[i * 8 + 7];
      const uint2 c00 = *(const uint2*)(sup_n + (size_t)a00 * CC + cof);
      const uint2 c01 = *(const uint2*)(sup_n + (size_t)a01 * CC + cof);
      const uint2 c10 = *(const uint2*)(sup_n + (size_t)a10 * CC + cof);
      const uint2 c11 = *(const uint2*)(sup_n + (size_t)a11 * CC + cof);
      val[i][0] = w00 * bflo(c00.x) + w01 * bflo(c01.x) + w10 * bflo(c10.x) + w11 * bflo(c11.x);
      val[i][1] = w00 * bfhi(c00.x) + w01 * bfhi(c01.x) + w10 * bfhi(c10.x) + w11 * bfhi(c11.x);
      val[i][2] = w00 * bflo(c00.y) + w01 * bflo(c01.y) + w10 * bflo(c10.y) + w11 * bflo(c11.y);
      val[i][3] = w00 * bfhi(c00.y) + w01 * bfhi(c01.y) + w10 * bfhi(c10.y) + w11 * bfhi(c11.y);
    }

#pragma unroll
    for (int o = 0; o < KTAP; ++o) {
      const uint2 wkw = *(const uint2*)(wkT + ((size_t)(o * KTAP + k)) * CC + cof);
      const float wk0 = bflo(wkw.x), wk1 = bfhi(wkw.x);
      const float wk2 = bflo(wkw.y), wk3 = bfhi(wkw.y);
#pragma unroll
      for (int i = 0; i < 2; ++i) {
        float a = acc[o][i];
        a = fmaf(val[i][0], wk0, a);
        a = fmaf(val[i][1], wk1, a);
        a = fmaf(val[i][2], wk2, a);
        a = fmaf(val[i][3], wk3, a);
        acc[o][i] = a;
      }
    }
  }

  // reduce across 64 lanes (sum over channels) + sigmoid + store
#pragma unroll
  for (int o = 0; o < KTAP; ++o)
#pragma unroll
    for (int i = 0; i < 2; ++i) {
      float s = acc[o][i];
#pragma unroll
      for (int m = 32; m; m >>= 1) s += __shfl_xor(s, m, 64);
      if (lane == 0)
        out[((size_t)n * KTAP + o) * HW + pq + i] = 1.f / (1.f + __expf(-s));
    }
}

extern "C" void kernel_launch(void* const* d_in, const int* in_sizes, int n_in,
                              void* d_out, int out_size, void* d_ws, size_t ws_size,
                              hipStream_t stream) {
  const float* support  = (const float*)d_in[0];
  const float* query    = (const float*)d_in[1];
  const float* w_off    = (const float*)d_in[2];
  const float* w_kernel = (const float*)d_in[3];
  float* out = (float*)d_out;

  // ws layout (floats). Region A holds offs_part (21.2 MB), then is reused
  // for supT bf16 (9.4 MB) after param_kernel consumed the partials.
  float* regionA = (float*)d_ws;
  float* offs_part = regionA;                                   // G1*NSZ f32
  unsigned short* supT = (unsigned short*)regionA;              // NN*HW*CC bf16 (aliases, later)
  float* tail      = regionA + (size_t)G1 * NSZ;
  unsigned short* Wm  = (unsigned short*)tail;                  // 409600 bf16 = 204800 f
  unsigned short* wkT = (unsigned short*)(tail + 204800);       // 20736 bf16 = 10368 f
  float* par = tail + 204800 + 10368;                           // NN*KTAP*HW*8 f

  prep_wm_kernel<<<(25 * 64 * 32 * 8 + 255) / 256, 256, 0, stream>>>(w_off, Wm);
  prep_wkt_kernel<<<(KTAP * KTAP * CC + 255) / 256, 256, 0, stream>>>(w_kernel, wkT);
  offset_conv_mfma<<<6 * NN * G1, 384, 0, stream>>>(support, query, Wm, offs_part);
  param_kernel<<<81 * NN, 256, 0, stream>>>(offs_part, par);
  transpose_kernel<<<8 * 72 * 8, 256, 0, stream>>>(support, supT);  // overwrites offs_part (dead)
  deform_kernel<<<288 * 8, 256, 0, stream>>>(supT, wkT, par, out);
}

// Round 8
// 102.497 us; speedup vs baseline: 6.3000x; 1.0227x over previous
//
#include <hip/hip_runtime.h>
#include <math.h>

#define NN 8
#define CC 256        // channels per tensor (concat input has 2*CC = 512)
#define HH 48
#define WW 48
#define HW 2304       // 48*48
#define OCONV 18      // offset-conv output channels (2*K)
#define KTAP 9        // deform taps
#define G1 16         // split-K groups for offset conv (512/16 = 32 ch/group)
#define NSZ (NN * OCONV * HW)   // 331776

#define TLR 12        // conv staged tile rows (8 + 4 halo)
#define TLC 52        // conv staged tile cols (48 + 4 halo)
#define NSITE (TLR * TLC)       // 624 spatial sites
#define SITE_B 80     // bytes per site: 32ch x bf16 = 64B + 16B pad

typedef __attribute__((ext_vector_type(8))) short short8;   // 8 bf16 (4 VGPRs)
typedef __attribute__((ext_vector_type(16))) float f32x16;  // 32x32 MFMA acc
typedef _Float16 h2 __attribute__((ext_vector_type(2)));    // packed f16 pair
typedef __fp16 fp16x2 __attribute__((ext_vector_type(2)));  // cvt_pkrtz native type

static __device__ __forceinline__ unsigned short f2bf(float f) {
  unsigned u = __float_as_uint(f);
  unsigned r = (u + 0x7fffu + ((u >> 16) & 1u)) >> 16;   // round-to-nearest-even
  return (unsigned short)r;
}
// pack two floats to f16 pair, return as dword
static __device__ __forceinline__ unsigned pkrtz(float a, float b) {
  fp16x2 h = __builtin_amdgcn_cvt_pkrtz(a, b);
  return *(const unsigned*)&h;
}

// ---------------------------------------------------------------------------
// Kernel 0a: w_off[18][512][5][5] -> MFMA A-fragment layout Wm[t][cb][o][j]
// ---------------------------------------------------------------------------
__global__ __launch_bounds__(256) void prep_wm_kernel(
    const float* __restrict__ w_off, unsigned short* __restrict__ Wm) {
  const int i = blockIdx.x * 256 + threadIdx.x;
  if (i >= 25 * 64 * 32 * 8) return;
  const int j  = i & 7;
  const int o  = (i >> 3) & 31;
  const int cb = (i >> 8) & 63;
  const int t  = i >> 14;
  float v = 0.f;
  if (o < OCONV) v = w_off[(size_t)(o * (2 * CC) + cb * 8 + j) * 25 + t];
  Wm[i] = f2bf(v);
}

// ---------------------------------------------------------------------------
// Kernel 0b: w_kernel[9][256][9] -> wkT[o][k][c] f16 (channel-last)
// ---------------------------------------------------------------------------
__global__ __launch_bounds__(256) void prep_wkt_kernel(
    const float* __restrict__ w_kernel, unsigned short* __restrict__ wkT) {
  const int i = blockIdx.x * 256 + threadIdx.x;
  if (i >= KTAP * KTAP * CC) return;
  const int c = i & 255;
  const int k = (i >> 8) % KTAP;
  const int o = i / (KTAP * 256);
  const _Float16 h = (_Float16)w_kernel[(size_t)(o * CC + c) * KTAP + k];  // RNE
  wkT[i] = *(const unsigned short*)&h;
}

// ---------------------------------------------------------------------------
// Kernel 1: offset conv as 25 shifted GEMMs, bf16 MFMA 32x32x16.
// XCD-pinned: n = bid % 8. (unchanged this round)
// ---------------------------------------------------------------------------
__global__ __launch_bounds__(384) void offset_conv_mfma(
    const float* __restrict__ support, const float* __restrict__ query,
    const unsigned short* __restrict__ Wm, float* __restrict__ offs_part) {
  const int bid = blockIdx.x;
  const int n    = bid & 7;          // XCD pin
  const int rest = bid >> 3;         // 0..95
  const int g  = rest / 6;           // K-group
  const int rb = rest % 6;           // row block
  const int tid = threadIdx.x;
  const int r0 = rb * 8;

  __shared__ __align__(16) char lds[NSITE * SITE_B];

  const float* src = (g < 8) ? (query + ((size_t)n * CC + g * 32) * HW)
                             : (support + ((size_t)n * CC + (g - 8) * 32) * HW);
  for (int cq = 0; cq < 8; ++cq) {
    const float* srcq = src + (size_t)(cq * 4) * HW;
    for (int s = tid; s < NSITE; s += 384) {
      const int rr = s / TLC, cc = s % TLC;
      const int gy = r0 - 2 + rr, gx = cc - 2;
      const bool ok = ((unsigned)gy < (unsigned)HH) && ((unsigned)gx < (unsigned)WW);
      const float* pp = srcq + gy * WW + gx;
      const float f0 = ok ? pp[0] : 0.f;
      const float f1 = ok ? pp[HW] : 0.f;
      const float f2 = ok ? pp[2 * HW] : 0.f;
      const float f3 = ok ? pp[3 * HW] : 0.f;
      const unsigned lo = (unsigned)f2bf(f0) | ((unsigned)f2bf(f1) << 16);
      const unsigned hi = (unsigned)f2bf(f2) | ((unsigned)f2bf(f3) << 16);
      *(uint2*)(lds + s * SITE_B + cq * 8) = make_uint2(lo, hi);
    }
  }
  __syncthreads();

  const int w      = tid >> 6;
  const int l      = tid & 63;
  const int lane31 = l & 31;
  const int half   = l >> 5;

  f32x16 acc0 = {0.f, 0.f, 0.f, 0.f, 0.f, 0.f, 0.f, 0.f,
                 0.f, 0.f, 0.f, 0.f, 0.f, 0.f, 0.f, 0.f};
  f32x16 acc1 = acc0;

  const int j0 = w * 64 + lane31;
  const int j1 = j0 + 32;
  const int base0 = ((j0 / 48) * TLC + (j0 % 48)) * SITE_B + half * 16;
  const int base1 = ((j1 / 48) * TLC + (j1 % 48)) * SITE_B + half * 16;

  const short8* __restrict__ wmp = (const short8*)Wm;
  const int wbase = g * 4 + half;

#pragma unroll
  for (int t = 0; t < 25; ++t) {
    const int u = t / 5, v = t % 5;
    const int off = u * (TLC * SITE_B) + v * SITE_B;
    const short8 a0 = wmp[(t * 64 + wbase) * 32 + lane31];
    const short8 a1 = wmp[(t * 64 + wbase + 2) * 32 + lane31];
    const short8 b00 = *(const short8*)(lds + base0 + off);
    const short8 b01 = *(const short8*)(lds + base0 + off + 32);
    const short8 b10 = *(const short8*)(lds + base1 + off);
    const short8 b11 = *(const short8*)(lds + base1 + off + 32);
    acc0 = __builtin_amdgcn_mfma_f32_32x32x16_bf16(a0, b00, acc0, 0, 0, 0);
    acc0 = __builtin_amdgcn_mfma_f32_32x32x16_bf16(a1, b01, acc0, 0, 0, 0);
    acc1 = __builtin_amdgcn_mfma_f32_32x32x16_bf16(a0, b10, acc1, 0, 0, 0);
    acc1 = __builtin_amdgcn_mfma_f32_32x32x16_bf16(a1, b11, acc1, 0, 0, 0);
  }

  float* dst = offs_part + ((size_t)(g * NN + n) * OCONV) * HW + r0 * WW;
#pragma unroll
  for (int r = 0; r < 16; ++r) {
    const int o = (r & 3) + 8 * (r >> 2) + 4 * half;
    if (o < OCONV) {
      dst[(size_t)o * HW + j0] = acc0[r];
      dst[(size_t)o * HW + j1] = acc1[r];
    }
  }
}

// ---------------------------------------------------------------------------
// Kernel 2: fold split-K offset partials + precompute bilinear params.
// par[n][k][p][8] dwords: {w00h2,w01h2,w10h2,w11h2 (f16 splat pairs),
//                          a00,a01,a10,a11}. XCD-pinned by n.
// ---------------------------------------------------------------------------
__global__ __launch_bounds__(256) void param_kernel(
    const float* __restrict__ offs_part, unsigned* __restrict__ par) {
  const int n  = blockIdx.x & 7;       // XCD pin
  const int j  = blockIdx.x >> 3;      // 0..80
  const int il = j * 256 + threadIdx.x; // 0..20735 within image
  const int p = il % HW;
  const int k = il / HW;
  const int y = p / WW, x = p % WW;

  float dy = 0.f, dx = 0.f;
#pragma unroll
  for (int g = 0; g < G1; ++g) {
    const float* base = offs_part + ((size_t)(g * NN + n) * OCONV + 2 * k) * HW + p;
    dy += base[0];
    dx += base[HW];
  }
  const float sy = (float)(y + k / 3 - 1) + dy;
  const float sx = (float)(x + k % 3 - 1) + dx;
  const float y0 = floorf(sy), x0 = floorf(sx);
  const float ly = sy - y0,  lx = sx - x0;
  const float y1 = y0 + 1.f, x1 = x0 + 1.f;
  const float vy0 = (y0 >= 0.f && y0 <= (float)(HH - 1)) ? 1.f : 0.f;
  const float vy1 = (y1 >= 0.f && y1 <= (float)(HH - 1)) ? 1.f : 0.f;
  const float vx0 = (x0 >= 0.f && x0 <= (float)(WW - 1)) ? 1.f : 0.f;
  const float vx1 = (x1 >= 0.f && x1 <= (float)(WW - 1)) ? 1.f : 0.f;
  const int yi0 = min(max((int)y0, 0), HH - 1);
  const int yi1 = min(max((int)y1, 0), HH - 1);
  const int xi0 = min(max((int)x0, 0), WW - 1);
  const int xi1 = min(max((int)x1, 0), WW - 1);

  const float w00 = (1.f - ly) * (1.f - lx) * vy0 * vx0;
  const float w01 = (1.f - ly) * lx * vy0 * vx1;
  const float w10 = ly * (1.f - lx) * vy1 * vx0;
  const float w11 = ly * lx * vy1 * vx1;

  unsigned* d = par + (size_t)(n * KTAP * HW + il) * 8;
  d[0] = pkrtz(w00, w00);
  d[1] = pkrtz(w01, w01);
  d[2] = pkrtz(w10, w10);
  d[3] = pkrtz(w11, w11);
  d[4] = (unsigned)(yi0 * WW + xi0);
  d[5] = (unsigned)(yi0 * WW + xi1);
  d[6] = (unsigned)(yi1 * WW + xi0);
  d[7] = (unsigned)(yi1 * WW + xi1);
}

// ---------------------------------------------------------------------------
// Kernel 3: transpose support[n][c][p] -> supT[n][p][c] in f16 (packed x2).
// XCD-pinned by n.
// ---------------------------------------------------------------------------
__global__ __launch_bounds__(256) void transpose_kernel(
    const float* __restrict__ support, unsigned short* __restrict__ supT) {
  const int bid = blockIdx.x;         // 4608 = 8 n * (72 ptiles * 8 ctiles)
  const int n    = bid & 7;           // XCD pin
  const int rest = bid >> 3;          // 0..575
  const int pt = rest % 72;
  const int ct = rest / 72;
  const int p0 = pt * 32, c0 = ct * 32;
  const int tid = threadIdx.x;

  __shared__ float tile[32][33];

  const float* src = support + ((size_t)n * CC + c0) * HW + p0;
#pragma unroll
  for (int j = 0; j < 4; ++j) {
    const int idx = tid + j * 256;
    const int cc = idx >> 5, pp = idx & 31;
    tile[pp][cc] = src[(size_t)cc * HW + pp];
  }
  __syncthreads();

  // write packed f16 pairs: 32 p-rows x 16 channel-pairs
#pragma unroll
  for (int j = 0; j < 2; ++j) {
    const int idx = tid + j * 256;
    const int pp = idx >> 4, cp = idx & 15;
    unsigned* dst = (unsigned*)(supT + ((size_t)(n * HW + p0 + pp)) * CC + c0);
    dst[cp] = pkrtz(tile[pp][2 * cp], tile[pp][2 * cp + 1]);
  }
}

// ---------------------------------------------------------------------------
// Kernel 4: deform gather + einsum + sigmoid. f16 supT/wkT, packed-f16 interp
// (v_pk_fma_f16) + v_dot2_f32_f16 einsum. Wave = 4 pixels, 64 lanes x 4 ch.
// XCD-pinned. 1152 blocks.
// ---------------------------------------------------------------------------
__global__ __launch_bounds__(256) void deform_kernel(
    const unsigned short* __restrict__ supT, const unsigned short* __restrict__ wkT,
    const unsigned* __restrict__ par, float* __restrict__ out) {
  const int tid  = threadIdx.x;
  const int wv   = __builtin_amdgcn_readfirstlane(tid >> 6);  // wave 0..3
  const int lane = tid & 63;
  const int bid  = blockIdx.x;        // 1152 = 144 chunks * 8 n
  const int n    = bid & 7;           // XCD pin
  const int pq   = (bid >> 3) * 16 + wv * 4;   // base pixel (4 px/wave)

  const unsigned short* sup_n = supT + (size_t)n * HW * CC;
  const int cof = lane * 4;           // this lane's 4 channels

  float acc[KTAP][4];
#pragma unroll
  for (int o = 0; o < KTAP; ++o)
#pragma unroll
    for (int i = 0; i < 4; ++i) acc[o][i] = 0.f;

  for (int k = 0; k < KTAP; ++k) {
    const uint4* pk = (const uint4*)(par + (size_t)((n * KTAP + k) * HW + pq) * 8);

    h2 va[4][2];
#pragma unroll
    for (int i = 0; i < 4; ++i) {
      const uint4 qw = pk[2 * i];       // wave-uniform -> s_load
      const uint4 qa = pk[2 * i + 1];
      const h2 w00 = *(const h2*)&qw.x, w01 = *(const h2*)&qw.y;
      const h2 w10 = *(const h2*)&qw.z, w11 = *(const h2*)&qw.w;
      const uint2 c00 = *(const uint2*)(sup_n + (size_t)qa.x * CC + cof);
      const uint2 c01 = *(const uint2*)(sup_n + (size_t)qa.y * CC + cof);
      const uint2 c10 = *(const uint2*)(sup_n + (size_t)qa.z * CC + cof);
      const uint2 c11 = *(const uint2*)(sup_n + (size_t)qa.w * CC + cof);
      h2 v0 = *(const h2*)&c00.x * w00;
      v0 += *(const h2*)&c01.x * w01;
      v0 += *(const h2*)&c10.x * w10;
      v0 += *(const h2*)&c11.x * w11;
      h2 v1 = *(const h2*)&c00.y * w00;
      v1 += *(const h2*)&c01.y * w01;
      v1 += *(const h2*)&c10.y * w10;
      v1 += *(const h2*)&c11.y * w11;
      va[i][0] = v0;
      va[i][1] = v1;
    }

#pragma unroll
    for (int o = 0; o < KTAP; ++o) {
      const uint2 wkw = *(const uint2*)(wkT + (size_t)(o * KTAP + k) * CC + cof);
      const h2 wl = *(const h2*)&wkw.x;
      const h2 wh = *(const h2*)&wkw.y;
#pragma unroll
      for (int i = 0; i < 4; ++i) {
        float a = acc[o][i];
#if __has_builtin(__builtin_amdgcn_fdot2)
        a = __builtin_amdgcn_fdot2(va[i][0], wl, a, false);
        a = __builtin_amdgcn_fdot2(va[i][1], wh, a, false);
#else
        a += (float)va[i][0][0] * (float)wl[0] + (float)va[i][0][1] * (float)wl[1];
        a += (float)va[i][1][0] * (float)wh[0] + (float)va[i][1][1] * (float)wh[1];
#endif
        acc[o][i] = a;
      }
    }
  }

  // reduce across 64 lanes (sum over channels) + sigmoid + store
#pragma unroll
  for (int o = 0; o < KTAP; ++o)
#pragma unroll
    for (int i = 0; i < 4; ++i) {
      float s = acc[o][i];
#pragma unroll
      for (int m = 32; m; m >>= 1) s += __shfl_xor(s, m, 64);
      if (lane == 0)
        out[((size_t)n * KTAP + o) * HW + pq + i] = 1.f / (1.f + __expf(-s));
    }
}

extern "C" void kernel_launch(void* const* d_in, const int* in_sizes, int n_in,
                              void* d_out, int out_size, void* d_ws, size_t ws_size,
                              hipStream_t stream) {
  const float* support  = (const float*)d_in[0];
  const float* query    = (const float*)d_in[1];
  const float* w_off    = (const float*)d_in[2];
  const float* w_kernel = (const float*)d_in[3];
  float* out = (float*)d_out;

  // ws layout (floats). Region A holds offs_part (21.2 MB), then is reused
  // for supT f16 (9.4 MB) after param_kernel consumed the partials.
  float* regionA = (float*)d_ws;
  float* offs_part = regionA;                                   // G1*NSZ f32
  unsigned short* supT = (unsigned short*)regionA;              // NN*HW*CC f16 (aliases, later)
  float* tail      = regionA + (size_t)G1 * NSZ;
  unsigned short* Wm  = (unsigned short*)tail;                  // 409600 bf16 = 204800 f
  unsigned short* wkT = (unsigned short*)(tail + 204800);       // 20736 f16 = 10368 f
  unsigned* par = (unsigned*)(tail + 204800 + 10368);           // NN*KTAP*HW*8 dwords

  prep_wm_kernel<<<(25 * 64 * 32 * 8 + 255) / 256, 256, 0, stream>>>(w_off, Wm);
  prep_wkt_kernel<<<(KTAP * KTAP * CC + 255) / 256, 256, 0, stream>>>(w_kernel, wkT);
  offset_conv_mfma<<<6 * NN * G1, 384, 0, stream>>>(support, query, Wm, offs_part);
  param_kernel<<<81 * NN, 256, 0, stream>>>(offs_part, par);
  transpose_kernel<<<8 * 72 * 8, 256, 0, stream>>>(support, supT);  // overwrites offs_part (dead)
  deform_kernel<<<144 * 8, 256, 0, stream>>>(supT, wkT, par, out);
}

// Round 9
// 74.852 us; speedup vs baseline: 8.6268x; 1.3693x over previous
//
#include <hip/hip_runtime.h>
#include <math.h>

#define NN 8
#define CC 256        // channels per tensor (concat input has 2*CC = 512)
#define HH 48
#define WW 48
#define HW 2304       // 48*48
#define OCONV 18      // offset-conv output channels (2*K)
#define KTAP 9        // deform taps
#define G1 16         // split-K groups for offset conv (512/16 = 32 ch/group)
#define NSZ (NN * OCONV * HW)   // 331776
#define MM 96         // padded GEMM rows (81 = 9k x 9o used)

#define TLR 12        // conv staged tile rows (8 + 4 halo)
#define TLC 52        // conv staged tile cols (48 + 4 halo)
#define NSITE (TLR * TLC)       // 624 spatial sites
#define SITE_B 80     // bytes per site: 32ch x bf16 = 64B + 16B pad

typedef __attribute__((ext_vector_type(8))) short short8;   // 8 bf16 (4 VGPRs)
typedef __attribute__((ext_vector_type(16))) float f32x16;  // 32x32 MFMA acc

static __device__ __forceinline__ unsigned short f2bf(float f) {
  unsigned u = __float_as_uint(f);
  unsigned r = (u + 0x7fffu + ((u >> 16) & 1u)) >> 16;   // round-to-nearest-even
  return (unsigned short)r;
}

// ---------------------------------------------------------------------------
// Kernel 0a: w_off[18][512][5][5] -> MFMA A-fragment layout Wm[t][cb][o][j]
// ---------------------------------------------------------------------------
__global__ __launch_bounds__(256) void prep_wm_kernel(
    const float* __restrict__ w_off, unsigned short* __restrict__ Wm) {
  const int i = blockIdx.x * 256 + threadIdx.x;
  if (i >= 25 * 64 * 32 * 8) return;
  const int j  = i & 7;
  const int o  = (i >> 3) & 31;
  const int cb = (i >> 8) & 63;
  const int t  = i >> 14;
  float v = 0.f;
  if (o < OCONV) v = w_off[(size_t)(o * (2 * CC) + cb * 8 + j) * 25 + t];
  Wm[i] = f2bf(v);
}

// ---------------------------------------------------------------------------
// Kernel 0b: w_kernel[9][256][9] -> wkm MFMA A-fragments (bf16), rows
// m = k*9+o (m<81, pad to 96): wkm[((mt*16+cb)*2+half)][r][j], c=cb*16+half*8+j
// ---------------------------------------------------------------------------
__global__ __launch_bounds__(256) void prep_wkm_kernel(
    const float* __restrict__ w_kernel, unsigned short* __restrict__ wkm) {
  const int i = blockIdx.x * 256 + threadIdx.x;
  if (i >= 3 * 16 * 2 * 32 * 8) return;
  const int j    = i & 7;
  const int r    = (i >> 3) & 31;
  const int half = (i >> 8) & 1;
  const int cb   = (i >> 9) & 15;
  const int mt   = i >> 13;
  const int m = mt * 32 + r;
  const int c = cb * 16 + half * 8 + j;
  float v = 0.f;
  if (m < 81) {
    const int k = m / 9, o = m % 9;
    v = w_kernel[(size_t)(o * CC + c) * KTAP + k];
  }
  wkm[i] = f2bf(v);
}

// ---------------------------------------------------------------------------
// Kernel 1: offset conv as 25 shifted GEMMs, bf16 MFMA 32x32x16.
// XCD-pinned: n = bid % 8. (unchanged)
// ---------------------------------------------------------------------------
__global__ __launch_bounds__(384) void offset_conv_mfma(
    const float* __restrict__ support, const float* __restrict__ query,
    const unsigned short* __restrict__ Wm, float* __restrict__ offs_part) {
  const int bid = blockIdx.x;
  const int n    = bid & 7;          // XCD pin
  const int rest = bid >> 3;         // 0..95
  const int g  = rest / 6;           // K-group
  const int rb = rest % 6;           // row block
  const int tid = threadIdx.x;
  const int r0 = rb * 8;

  __shared__ __align__(16) char lds[NSITE * SITE_B];

  const float* src = (g < 8) ? (query + ((size_t)n * CC + g * 32) * HW)
                             : (support + ((size_t)n * CC + (g - 8) * 32) * HW);
  for (int cq = 0; cq < 8; ++cq) {
    const float* srcq = src + (size_t)(cq * 4) * HW;
    for (int s = tid; s < NSITE; s += 384) {
      const int rr = s / TLC, cc = s % TLC;
      const int gy = r0 - 2 + rr, gx = cc - 2;
      const bool ok = ((unsigned)gy < (unsigned)HH) && ((unsigned)gx < (unsigned)WW);
      const float* pp = srcq + gy * WW + gx;
      const float f0 = ok ? pp[0] : 0.f;
      const float f1 = ok ? pp[HW] : 0.f;
      const float f2 = ok ? pp[2 * HW] : 0.f;
      const float f3 = ok ? pp[3 * HW] : 0.f;
      const unsigned lo = (unsigned)f2bf(f0) | ((unsigned)f2bf(f1) << 16);
      const unsigned hi = (unsigned)f2bf(f2) | ((unsigned)f2bf(f3) << 16);
      *(uint2*)(lds + s * SITE_B + cq * 8) = make_uint2(lo, hi);
    }
  }
  __syncthreads();

  const int w      = tid >> 6;
  const int l      = tid & 63;
  const int lane31 = l & 31;
  const int half   = l >> 5;

  f32x16 acc0 = {0.f, 0.f, 0.f, 0.f, 0.f, 0.f, 0.f, 0.f,
                 0.f, 0.f, 0.f, 0.f, 0.f, 0.f, 0.f, 0.f};
  f32x16 acc1 = acc0;

  const int j0 = w * 64 + lane31;
  const int j1 = j0 + 32;
  const int base0 = ((j0 / 48) * TLC + (j0 % 48)) * SITE_B + half * 16;
  const int base1 = ((j1 / 48) * TLC + (j1 % 48)) * SITE_B + half * 16;

  const short8* __restrict__ wmp = (const short8*)Wm;
  const int wbase = g * 4 + half;

#pragma unroll
  for (int t = 0; t < 25; ++t) {
    const int u = t / 5, v = t % 5;
    const int off = u * (TLC * SITE_B) + v * SITE_B;
    const short8 a0 = wmp[(t * 64 + wbase) * 32 + lane31];
    const short8 a1 = wmp[(t * 64 + wbase + 2) * 32 + lane31];
    const short8 b00 = *(const short8*)(lds + base0 + off);
    const short8 b01 = *(const short8*)(lds + base0 + off + 32);
    const short8 b10 = *(const short8*)(lds + base1 + off);
    const short8 b11 = *(const short8*)(lds + base1 + off + 32);
    acc0 = __builtin_amdgcn_mfma_f32_32x32x16_bf16(a0, b00, acc0, 0, 0, 0);
    acc0 = __builtin_amdgcn_mfma_f32_32x32x16_bf16(a1, b01, acc0, 0, 0, 0);
    acc1 = __builtin_amdgcn_mfma_f32_32x32x16_bf16(a0, b10, acc1, 0, 0, 0);
    acc1 = __builtin_amdgcn_mfma_f32_32x32x16_bf16(a1, b11, acc1, 0, 0, 0);
  }

  float* dst = offs_part + ((size_t)(g * NN + n) * OCONV) * HW + r0 * WW;
#pragma unroll
  for (int r = 0; r < 16; ++r) {
    const int o = (r & 3) + 8 * (r >> 2) + 4 * half;
    if (o < OCONV) {
      dst[(size_t)o * HW + j0] = acc0[r];
      dst[(size_t)o * HW + j1] = acc1[r];
    }
  }
}

// ---------------------------------------------------------------------------
// Kernel 2: fold split-K offset partials + precompute bilinear params.
// par[n][k][p][8]: {w00,w01,w10,w11 (f32), a00,a01,a10,a11 (int)}. XCD-pinned.
// ---------------------------------------------------------------------------
__global__ __launch_bounds__(256) void param_kernel(
    const float* __restrict__ offs_part, float* __restrict__ par) {
  const int n  = blockIdx.x & 7;       // XCD pin
  const int j  = blockIdx.x >> 3;      // 0..80
  const int il = j * 256 + threadIdx.x; // 0..20735 within image
  const int p = il % HW;
  const int k = il / HW;
  const int y = p / WW, x = p % WW;

  float dy = 0.f, dx = 0.f;
#pragma unroll
  for (int g = 0; g < G1; ++g) {
    const float* base = offs_part + ((size_t)(g * NN + n) * OCONV + 2 * k) * HW + p;
    dy += base[0];
    dx += base[HW];
  }
  const float sy = (float)(y + k / 3 - 1) + dy;
  const float sx = (float)(x + k % 3 - 1) + dx;
  const float y0 = floorf(sy), x0 = floorf(sx);
  const float ly = sy - y0,  lx = sx - x0;
  const float y1 = y0 + 1.f, x1 = x0 + 1.f;
  const float vy0 = (y0 >= 0.f && y0 <= (float)(HH - 1)) ? 1.f : 0.f;
  const float vy1 = (y1 >= 0.f && y1 <= (float)(HH - 1)) ? 1.f : 0.f;
  const float vx0 = (x0 >= 0.f && x0 <= (float)(WW - 1)) ? 1.f : 0.f;
  const float vx1 = (x1 >= 0.f && x1 <= (float)(WW - 1)) ? 1.f : 0.f;
  const int yi0 = min(max((int)y0, 0), HH - 1);
  const int yi1 = min(max((int)y1, 0), HH - 1);
  const int xi0 = min(max((int)x0, 0), WW - 1);
  const int xi1 = min(max((int)x1, 0), WW - 1);

  float* d = par + ((size_t)n * KTAP * HW + il) * 8;
  d[0] = (1.f - ly) * (1.f - lx) * vy0 * vx0;
  d[1] = (1.f - ly) * lx * vy0 * vx1;
  d[2] = ly * (1.f - lx) * vy1 * vx0;
  d[3] = ly * lx * vy1 * vx1;
  int* di = (int*)d;
  di[4] = yi0 * WW + xi0;
  di[5] = yi0 * WW + xi1;
  di[6] = yi1 * WW + xi0;
  di[7] = yi1 * WW + xi1;
}

// ---------------------------------------------------------------------------
// Kernel 3: transpose support[n][c][p] -> supT[n][p][c] in bf16 (packed x2).
// XCD-pinned by n.
// ---------------------------------------------------------------------------
__global__ __launch_bounds__(256) void transpose_kernel(
    const float* __restrict__ support, unsigned short* __restrict__ supT) {
  const int bid = blockIdx.x;         // 4608 = 8 n * (72 ptiles * 8 ctiles)
  const int n    = bid & 7;           // XCD pin
  const int rest = bid >> 3;          // 0..575
  const int pt = rest % 72;
  const int ct = rest / 72;
  const int p0 = pt * 32, c0 = ct * 32;
  const int tid = threadIdx.x;

  __shared__ float tile[32][33];

  const float* src = support + ((size_t)n * CC + c0) * HW + p0;
#pragma unroll
  for (int j = 0; j < 4; ++j) {
    const int idx = tid + j * 256;
    const int cc = idx >> 5, pp = idx & 31;
    tile[pp][cc] = src[(size_t)cc * HW + pp];
  }
  __syncthreads();

  // write packed bf16 pairs: 32 p-rows x 16 channel-pairs
#pragma unroll
  for (int j = 0; j < 2; ++j) {
    const int idx = tid + j * 256;
    const int pp = idx >> 4, cp = idx & 15;
    const unsigned lo = f2bf(tile[pp][2 * cp]);
    const unsigned hi = f2bf(tile[pp][2 * cp + 1]);
    unsigned* dst = (unsigned*)(supT + ((size_t)(n * HW + p0 + pp)) * CC + c0);
    dst[cp] = lo | (hi << 16);
  }
}

// ---------------------------------------------------------------------------
// Kernel 4: D[n][m][site] = sum_c wk[o][c][k] * sup[n][c][site], m=k*9+o.
// bf16 MFMA 32x32x16, B = supT rows (16B contiguous frags), A = wkm frags.
// One wave = one (m-tile, site-tile). Grid 432 = 54 x 8n, XCD-pinned.
// ---------------------------------------------------------------------------
__global__ __launch_bounds__(256) void deform_gemm(
    const unsigned short* __restrict__ supT, const unsigned short* __restrict__ wkm,
    float* __restrict__ D) {
  const int bid = blockIdx.x;
  const int n    = bid & 7;           // XCD pin
  const int rest = bid >> 3;          // 0..53
  const int tid = threadIdx.x;
  const int w = tid >> 6;
  const int wid = rest * 4 + w;       // 0..215
  const int st = wid % 72;            // site tile
  const int mt = wid / 72;            // m tile 0..2
  const int l = tid & 63;
  const int lane31 = l & 31;
  const int half = l >> 5;
  const int site0 = st * 32;

  const unsigned short* bsrc =
      supT + ((size_t)n * HW + site0 + lane31) * CC + half * 8;
  const unsigned short* asrc = wkm + (size_t)(half * 32 + lane31) * 8;

  f32x16 acc = {0.f, 0.f, 0.f, 0.f, 0.f, 0.f, 0.f, 0.f,
                0.f, 0.f, 0.f, 0.f, 0.f, 0.f, 0.f, 0.f};

#pragma unroll
  for (int cb = 0; cb < 16; ++cb) {
    const short8 b = *(const short8*)(bsrc + cb * 16);
    const short8 a = *(const short8*)(asrc + (size_t)((mt * 16 + cb) * 2) * 256);
    acc = __builtin_amdgcn_mfma_f32_32x32x16_bf16(a, b, acc, 0, 0, 0);
  }

  float* Dn = D + (size_t)n * MM * HW;
#pragma unroll
  for (int r = 0; r < 16; ++r) {
    const int m = mt * 32 + (r & 3) + 8 * (r >> 2) + 4 * half;
    Dn[(size_t)m * HW + site0 + lane31] = acc[r];
  }
}

// ---------------------------------------------------------------------------
// Kernel 5: combine: out[n,o,p] = sigmoid( sum_k sum_corner w * D[n][k*9+o][site] )
// One thread per output element. No reduction. XCD-pinned.
// ---------------------------------------------------------------------------
__global__ __launch_bounds__(256) void deform_combine(
    const float* __restrict__ D, const float* __restrict__ par,
    float* __restrict__ out) {
  const int bid = blockIdx.x;          // 648 = 81 * 8n
  const int n  = bid & 7;              // XCD pin
  const int rr = bid >> 3;             // 0..80
  const int o  = rr / 9;
  const int p  = (rr % 9) * 256 + threadIdx.x;

  const float* Dn = D + (size_t)n * MM * HW;
  const float* pb = par + ((size_t)n * KTAP * HW + p) * 8;

  float s = 0.f;
#pragma unroll
  for (int k = 0; k < KTAP; ++k) {
    const float4 wv = *(const float4*)(pb + (size_t)k * HW * 8);
    const int4  av = *(const int4*)(pb + (size_t)k * HW * 8 + 4);
    const float* base = Dn + (size_t)(k * 9 + o) * HW;
    s += wv.x * base[av.x] + wv.y * base[av.y] +
         wv.z * base[av.z] + wv.w * base[av.w];
  }
  out[((size_t)n * KTAP + o) * HW + p] = 1.f / (1.f + __expf(-s));
}

extern "C" void kernel_launch(void* const* d_in, const int* in_sizes, int n_in,
                              void* d_out, int out_size, void* d_ws, size_t ws_size,
                              hipStream_t stream) {
  const float* support  = (const float*)d_in[0];
  const float* query    = (const float*)d_in[1];
  const float* w_off    = (const float*)d_in[2];
  const float* w_kernel = (const float*)d_in[3];
  float* out = (float*)d_out;

  // ws layout (floats). Region A (21.2MB) holds offs_part early; after
  // param_kernel it is reused for supT (9.4MB bf16) + D (7.1MB f32).
  float* regionA = (float*)d_ws;
  float* offs_part = regionA;                                   // G1*NSZ f32 (early)
  unsigned short* supT = (unsigned short*)regionA;              // NN*HW*CC bf16 (late)
  float* D = regionA + (size_t)NN * HW * CC / 2;                // NN*MM*HW f32 (late)
  float* tail      = regionA + (size_t)G1 * NSZ;
  unsigned short* Wm  = (unsigned short*)tail;                  // 409600 bf16 = 204800 f
  float* par = tail + 204800;                                   // NN*KTAP*HW*8 f = 1327104 f
  unsigned short* wkm = (unsigned short*)(par + (size_t)NN * KTAP * HW * 8);  // 49152 bf16

  prep_wm_kernel<<<(25 * 64 * 32 * 8 + 255) / 256, 256, 0, stream>>>(w_off, Wm);
  prep_wkm_kernel<<<(3 * 16 * 2 * 32 * 8 + 255) / 256, 256, 0, stream>>>(w_kernel, wkm);
  offset_conv_mfma<<<6 * NN * G1, 384, 0, stream>>>(support, query, Wm, offs_part);
  param_kernel<<<81 * NN, 256, 0, stream>>>(offs_part, par);
  transpose_kernel<<<8 * 72 * 8, 256, 0, stream>>>(support, supT);  // kills offs_part (dead)
  deform_gemm<<<54 * 8, 256, 0, stream>>>(supT, wkm, D);
  deform_combine<<<81 * 8, 256, 0, stream>>>(D, par, out);
}